// Round 1
// baseline (4996.609 us; speedup 1.0000x reference)
//
#include <hip/hip_runtime.h>
#include <hip/hip_bf16.h>

#define TT 4096
#define SS 2048
#define BBATCH 2
#define DM 1024
#define NH 16
#define HD 64
#define FFD 4096
#define NL 4
#define VV 18691
#define VP 18816

typedef __bf16 bf16x8 __attribute__((ext_vector_type(8)));
typedef float f32x4 __attribute__((ext_vector_type(4)));

__device__ __forceinline__ float bfb2f(unsigned short u) {
    union { unsigned int i; float f; } x;
    x.i = ((unsigned int)u) << 16;
    return x.f;
}
__device__ __forceinline__ unsigned short f2bfb(float f) {
    union { float f; unsigned int i; } x;
    x.f = f;
    unsigned int r = 0x7fffu + ((x.i >> 16) & 1u);
    x.i += r;
    return (unsigned short)(x.i >> 16);
}
__device__ __forceinline__ unsigned int pack2(float lo, float hi) {
    return (unsigned int)f2bfb(lo) | ((unsigned int)f2bfb(hi) << 16);
}

__device__ __forceinline__ float wave_sum(float v) {
#pragma unroll
    for (int o = 32; o; o >>= 1) v += __shfl_xor(v, o, 64);
    return v;
}

// 256-thread block sum
__device__ __forceinline__ float block_sum256(float v) {
    __shared__ float sb[4];
    v = wave_sum(v);
    int wid = threadIdx.x >> 6;
    if ((threadIdx.x & 63) == 0) sb[wid] = v;
    __syncthreads();
    float t = sb[0] + sb[1] + sb[2] + sb[3];
    __syncthreads();
    return t;
}

// x = rms_norm(wte[idx]); x0 = bf16(x); levels[t]
__global__ __launch_bounds__(256) void embed_kernel(
    const int* __restrict__ idx, const float* __restrict__ wte,
    float* __restrict__ x, unsigned short* __restrict__ x0, int* __restrict__ levels)
{
    int t = blockIdx.x;
    int id = idx[t];
    const float* row = wte + (size_t)id * DM;
    float4 v = *reinterpret_cast<const float4*>(row + threadIdx.x * 4);
    float ss = v.x * v.x + v.y * v.y + v.z * v.z + v.w * v.w;
    float tot = block_sum256(ss);
    float rs = rsqrtf(tot / (float)DM + 1e-6f);
    float4 o;
    o.x = v.x * rs; o.y = v.y * rs; o.z = v.z * rs; o.w = v.w * rs;
    size_t off = (size_t)t * DM + threadIdx.x * 4;
    *reinterpret_cast<float4*>(x + off) = o;
    ushort4 ub;
    ub.x = f2bfb(o.x); ub.y = f2bfb(o.y); ub.z = f2bfb(o.z); ub.w = f2bfb(o.w);
    *reinterpret_cast<ushort4*>(x0 + off) = ub;
    if (threadIdx.x == 0) levels[t] = (id >= 16385) + (id >= 18434);
}

// xr = l0*x + l1*x0 (written back to x); out = bf16(rms_norm(xr))
__global__ __launch_bounds__(256) void mixnorm_kernel(
    float* __restrict__ x, const unsigned short* __restrict__ x0,
    const float* __restrict__ lam2, unsigned short* __restrict__ out)
{
    int t = blockIdx.x;
    size_t off = (size_t)t * DM + threadIdx.x * 4;
    float4 xv = *reinterpret_cast<const float4*>(x + off);
    float l0 = lam2[0], l1 = lam2[1];
    ushort4 u = *reinterpret_cast<const ushort4*>(x0 + off);
    float4 r;
    r.x = l0 * xv.x + l1 * bfb2f(u.x);
    r.y = l0 * xv.y + l1 * bfb2f(u.y);
    r.z = l0 * xv.z + l1 * bfb2f(u.z);
    r.w = l0 * xv.w + l1 * bfb2f(u.w);
    float ss = r.x * r.x + r.y * r.y + r.z * r.z + r.w * r.w;
    float tot = block_sum256(ss);
    float rs = rsqrtf(tot / (float)DM + 1e-6f);
    *reinterpret_cast<float4*>(x + off) = r;
    ushort4 ob;
    ob.x = f2bfb(r.x * rs); ob.y = f2bfb(r.y * rs);
    ob.z = f2bfb(r.z * rs); ob.w = f2bfb(r.w * rs);
    *reinterpret_cast<ushort4*>(out + off) = ob;
}

// out = bf16(rms_norm(x)), x unmodified
__global__ __launch_bounds__(256) void norm_kernel(
    const float* __restrict__ x, unsigned short* __restrict__ out)
{
    int t = blockIdx.x;
    size_t off = (size_t)t * DM + threadIdx.x * 4;
    float4 r = *reinterpret_cast<const float4*>(x + off);
    float ss = r.x * r.x + r.y * r.y + r.z * r.z + r.w * r.w;
    float tot = block_sum256(ss);
    float rs = rsqrtf(tot / (float)DM + 1e-6f);
    ushort4 ob;
    ob.x = f2bfb(r.x * rs); ob.y = f2bfb(r.y * rs);
    ob.z = f2bfb(r.z * rs); ob.w = f2bfb(r.w * rs);
    *reinterpret_cast<ushort4*>(out + off) = ob;
}

// C = A(bf16 [M][K]) @ W^T, W = fp32 [N][K].
// EPI 0: C bf16.  EPI 1: C bf16 = relu(acc)^2.  EPI 2: Cf(fp32) += acc (in-place residual).
template <int EPI>
__global__ __launch_bounds__(256) void gemm_bt(
    const unsigned short* __restrict__ A, const float* __restrict__ Bw,
    unsigned short* __restrict__ Cb, float* __restrict__ Cf,
    int M, int N, int K, int ldC)
{
    __shared__ unsigned short As[128][40];
    __shared__ unsigned short Bs[128][40];
    int tid = threadIdx.x;
    int lane = tid & 63, wave = tid >> 6;
    int wr = wave >> 1, wc = wave & 1;
    int m0 = blockIdx.y * 128, n0 = blockIdx.x * 128;
    int sr = tid >> 2, scc = (tid & 3) * 8;

    const unsigned short* pA0 = A + (size_t)(m0 + sr) * K + scc;
    const unsigned short* pA1 = A + (size_t)(m0 + sr + 64) * K + scc;
    const float* pB0 = Bw + (size_t)(n0 + sr) * K + scc;
    const float* pB1 = Bw + (size_t)(n0 + sr + 64) * K + scc;
    bool ok0 = (n0 + sr) < N, ok1 = (n0 + sr + 64) < N;

    f32x4 acc[4][4];
#pragma unroll
    for (int m = 0; m < 4; ++m)
#pragma unroll
        for (int n = 0; n < 4; ++n) acc[m][n] = 0.0f;

    int fr = lane & 15, fchunk = (lane >> 4) * 8;

    for (int kt = 0; kt < K; kt += 32) {
        int4 av0 = *reinterpret_cast<const int4*>(pA0 + kt);
        int4 av1 = *reinterpret_cast<const int4*>(pA1 + kt);
        float4 b00 = {0, 0, 0, 0}, b01 = {0, 0, 0, 0}, b10 = {0, 0, 0, 0}, b11 = {0, 0, 0, 0};
        if (ok0) { b00 = *reinterpret_cast<const float4*>(pB0 + kt); b01 = *reinterpret_cast<const float4*>(pB0 + kt + 4); }
        if (ok1) { b10 = *reinterpret_cast<const float4*>(pB1 + kt); b11 = *reinterpret_cast<const float4*>(pB1 + kt + 4); }
        __syncthreads();
        *reinterpret_cast<int4*>(&As[sr][scc]) = av0;
        *reinterpret_cast<int4*>(&As[sr + 64][scc]) = av1;
        uint4 bp0, bp1;
        bp0.x = pack2(b00.x, b00.y); bp0.y = pack2(b00.z, b00.w);
        bp0.z = pack2(b01.x, b01.y); bp0.w = pack2(b01.z, b01.w);
        bp1.x = pack2(b10.x, b10.y); bp1.y = pack2(b10.z, b10.w);
        bp1.z = pack2(b11.x, b11.y); bp1.w = pack2(b11.z, b11.w);
        *reinterpret_cast<uint4*>(&Bs[sr][scc]) = bp0;
        *reinterpret_cast<uint4*>(&Bs[sr + 64][scc]) = bp1;
        __syncthreads();
        bf16x8 af[4], bfv[4];
#pragma unroll
        for (int m = 0; m < 4; ++m)
            af[m] = *reinterpret_cast<const bf16x8*>(&As[wr * 64 + m * 16 + fr][fchunk]);
#pragma unroll
        for (int n = 0; n < 4; ++n)
            bfv[n] = *reinterpret_cast<const bf16x8*>(&Bs[wc * 64 + n * 16 + fr][fchunk]);
#pragma unroll
        for (int m = 0; m < 4; ++m)
#pragma unroll
            for (int n = 0; n < 4; ++n)
                acc[m][n] = __builtin_amdgcn_mfma_f32_16x16x32_bf16(af[m], bfv[n], acc[m][n], 0, 0, 0);
    }

    int rb = m0 + wr * 64 + (lane >> 4) * 4;
    int cb = n0 + wc * 64 + (lane & 15);
#pragma unroll
    for (int n = 0; n < 4; ++n) {
        int gc = cb + n * 16;
        if (gc >= N) continue;
#pragma unroll
        for (int m = 0; m < 4; ++m) {
#pragma unroll
            for (int j = 0; j < 4; ++j) {
                int gr = rb + m * 16 + j;
                float val = acc[m][n][j];
                if constexpr (EPI == 0) {
                    Cb[(size_t)gr * ldC + gc] = f2bfb(val);
                } else if constexpr (EPI == 1) {
                    float rl = fmaxf(val, 0.0f);
                    Cb[(size_t)gr * ldC + gc] = f2bfb(rl * rl);
                } else {
                    size_t o = (size_t)gr * ldC + gc;
                    Cf[o] = Cf[o] + val;
                }
            }
        }
    }
}

__global__ void vcopy_kernel(const unsigned short* __restrict__ v, unsigned short* __restrict__ v1)
{
    int i = blockIdx.x * 256 + threadIdx.x;
    reinterpret_cast<ushort4*>(v1)[i] = reinterpret_cast<const ushort4*>(v)[i];
}

__global__ void vmix_kernel(unsigned short* __restrict__ v, const unsigned short* __restrict__ v1,
                            const float* __restrict__ lamb)
{
    int i = blockIdx.x * 256 + threadIdx.x;
    float la = *lamb;
    ushort4 a = reinterpret_cast<const ushort4*>(v)[i];
    ushort4 b = reinterpret_cast<const ushort4*>(v1)[i];
    ushort4 o;
    o.x = f2bfb((1.0f - la) * bfb2f(a.x) + la * bfb2f(b.x));
    o.y = f2bfb((1.0f - la) * bfb2f(a.y) + la * bfb2f(b.y));
    o.z = f2bfb((1.0f - la) * bfb2f(a.z) + la * bfb2f(b.z));
    o.w = f2bfb((1.0f - la) * bfb2f(a.w) + la * bfb2f(b.w));
    reinterpret_cast<ushort4*>(v)[i] = o;
}

// per-(t,h) head rms_norm + rotary; applied in-place to q (blockIdx.y==0) or k (==1)
__global__ __launch_bounds__(256) void rope_kernel(unsigned short* __restrict__ q,
                                                   unsigned short* __restrict__ k)
{
    int wid = threadIdx.x >> 6, lane = threadIdx.x & 63;
    int id = blockIdx.x * 4 + wid; // t*NH + h
    unsigned short* p = blockIdx.y ? k : q;
    int t = id >> 4, h = id & 15;
    int s = t & (SS - 1);
    size_t off = (size_t)t * DM + h * HD + lane;
    float val = bfb2f(p[off]);
    float ss = wave_sum(val * val);
    float rs = rsqrtf(ss / (float)HD + 1e-6f);
    float nv = val * rs;
    float other = __shfl_xor(nv, 32, 64);
    int j = lane & 31;
    // inv_freq = 10000^(-j/32) = exp2(-j * log2(10000)/32)
    float invf = exp2f(-(float)j * 0.41524101186092025f);
    float fr = (float)s * invf;
    float sn, cs;
    sincosf(fr, &sn, &cs);
    float outv = (lane < 32) ? (nv * cs + other * sn) : (nv * cs - other * sn);
    p[off] = f2bfb(outv);
}

// flash-style attention, VALU. block = 128 threads, 64 queries per block.
// thread: g = tid&3 (16 key-cols), qp = tid>>2 (2 query rows).
__global__ __launch_bounds__(128) void attn_kernel(
    const unsigned short* __restrict__ q, const unsigned short* __restrict__ k,
    const unsigned short* __restrict__ v, unsigned short* __restrict__ y,
    const int* __restrict__ levels)
{
    __shared__ float Qs[64][68];
    __shared__ float Ks[64][68];
    __shared__ float Vs[64][68];
    __shared__ float Ps[64][68];
    int bh = blockIdx.x;
    int b = bh >> 4, h = bh & 15;
    int q0 = blockIdx.y * 64;
    size_t base = (size_t)b * SS * DM + h * HD;
    int tid = threadIdx.x;

    for (int i = tid; i < 1024; i += 128) {
        int r = i >> 4, c4 = (i & 15) * 4;
        ushort4 u = *reinterpret_cast<const ushort4*>(q + base + (size_t)(q0 + r) * DM + c4);
        float4 f;
        f.x = bfb2f(u.x); f.y = bfb2f(u.y); f.z = bfb2f(u.z); f.w = bfb2f(u.w);
        *reinterpret_cast<float4*>(&Qs[r][c4]) = f;
    }

    int g = tid & 3, qp = tid >> 2;
    int qi0 = qp * 2, qi1 = qi0 + 1;
    int qg0 = q0 + qi0, qg1 = q0 + qi1;
    float m0r = -1e30f, m1r = -1e30f, l0r = 0.0f, l1r = 0.0f;
    float acc0[16], acc1[16];
#pragma unroll
    for (int d = 0; d < 16; ++d) { acc0[d] = 0.0f; acc1[d] = 0.0f; }

    int nch = q0 / 64 + 1;
    for (int kc = 0; kc < nch; ++kc) {
        int k0 = kc * 64;
        __syncthreads();
        for (int i = tid; i < 1024; i += 128) {
            int r = i >> 4, c4 = (i & 15) * 4;
            size_t goff = base + (size_t)(k0 + r) * DM + c4;
            ushort4 uk = *reinterpret_cast<const ushort4*>(k + goff);
            ushort4 uv = *reinterpret_cast<const ushort4*>(v + goff);
            float4 fk, fv;
            fk.x = bfb2f(uk.x); fk.y = bfb2f(uk.y); fk.z = bfb2f(uk.z); fk.w = bfb2f(uk.w);
            fv.x = bfb2f(uv.x); fv.y = bfb2f(uv.y); fv.z = bfb2f(uv.z); fv.w = bfb2f(uv.w);
            *reinterpret_cast<float4*>(&Ks[r][c4]) = fk;
            *reinterpret_cast<float4*>(&Vs[r][c4]) = fv;
        }
        __syncthreads();

        float sc0[16], sc1[16];
#pragma unroll
        for (int j = 0; j < 16; ++j) { sc0[j] = 0.0f; sc1[j] = 0.0f; }
        for (int d4 = 0; d4 < 16; ++d4) {
            float4 q0v = *reinterpret_cast<const float4*>(&Qs[qi0][d4 * 4]);
            float4 q1v = *reinterpret_cast<const float4*>(&Qs[qi1][d4 * 4]);
#pragma unroll
            for (int j = 0; j < 16; ++j) {
                float4 kv = *reinterpret_cast<const float4*>(&Ks[g * 16 + j][d4 * 4]);
                sc0[j] += q0v.x * kv.x + q0v.y * kv.y + q0v.z * kv.z + q0v.w * kv.w;
                sc1[j] += q1v.x * kv.x + q1v.y * kv.y + q1v.z * kv.z + q1v.w * kv.w;
            }
        }
        float cm0 = -1e30f, cm1 = -1e30f;
#pragma unroll
        for (int j = 0; j < 16; ++j) {
            int kg = k0 + g * 16 + j;
            int lv = levels[b * SS + kg];
            bool va = (kg <= qg0) && (lv > 0 || (qg0 - kg) <= 256);
            bool vb = (kg <= qg1) && (lv > 0 || (qg1 - kg) <= 256);
            sc0[j] = va ? sc0[j] * 0.125f : -1e30f;
            sc1[j] = vb ? sc1[j] * 0.125f : -1e30f;
            cm0 = fmaxf(cm0, sc0[j]);
            cm1 = fmaxf(cm1, sc1[j]);
        }
        cm0 = fmaxf(cm0, __shfl_xor(cm0, 1, 64)); cm0 = fmaxf(cm0, __shfl_xor(cm0, 2, 64));
        cm1 = fmaxf(cm1, __shfl_xor(cm1, 1, 64)); cm1 = fmaxf(cm1, __shfl_xor(cm1, 2, 64));
        float nm0 = fmaxf(m0r, cm0), nm1 = fmaxf(m1r, cm1);
        float s0 = __expf(m0r - nm0), s1 = __expf(m1r - nm1);
        float ps0 = 0.0f, ps1 = 0.0f;
#pragma unroll
        for (int j = 0; j < 16; ++j) {
            float p0 = (sc0[j] > -1e29f) ? __expf(sc0[j] - nm0) : 0.0f;
            float p1 = (sc1[j] > -1e29f) ? __expf(sc1[j] - nm1) : 0.0f;
            Ps[qi0][g * 16 + j] = p0;
            Ps[qi1][g * 16 + j] = p1;
            ps0 += p0; ps1 += p1;
        }
        ps0 += __shfl_xor(ps0, 1, 64); ps0 += __shfl_xor(ps0, 2, 64);
        ps1 += __shfl_xor(ps1, 1, 64); ps1 += __shfl_xor(ps1, 2, 64);
        l0r = l0r * s0 + ps0;
        l1r = l1r * s1 + ps1;
        m0r = nm0; m1r = nm1;
#pragma unroll
        for (int d = 0; d < 16; ++d) { acc0[d] *= s0; acc1[d] *= s1; }
        __syncthreads(); // Ps visibility across the 4-thread cluster
        for (int kk = 0; kk < 64; ++kk) {
            float p0 = Ps[qi0][kk], p1 = Ps[qi1][kk];
#pragma unroll
            for (int d4 = 0; d4 < 4; ++d4) {
                float4 vv = *reinterpret_cast<const float4*>(&Vs[kk][g * 16 + d4 * 4]);
                acc0[d4 * 4 + 0] += p0 * vv.x; acc0[d4 * 4 + 1] += p0 * vv.y;
                acc0[d4 * 4 + 2] += p0 * vv.z; acc0[d4 * 4 + 3] += p0 * vv.w;
                acc1[d4 * 4 + 0] += p1 * vv.x; acc1[d4 * 4 + 1] += p1 * vv.y;
                acc1[d4 * 4 + 2] += p1 * vv.z; acc1[d4 * 4 + 3] += p1 * vv.w;
            }
        }
    }
    float i0 = 1.0f / l0r, i1 = 1.0f / l1r;
#pragma unroll
    for (int d = 0; d < 16; ++d) {
        y[base + (size_t)qg0 * DM + g * 16 + d] = f2bfb(acc0[d] * i0);
        y[base + (size_t)qg1 * DM + g * 16 + d] = f2bfb(acc1[d] * i1);
    }
}

// per-token: softcap + logsumexp + NLL
__global__ __launch_bounds__(256) void loss_kernel(
    const unsigned short* __restrict__ logits, const int* __restrict__ target,
    float* __restrict__ out)
{
    int t = blockIdx.x;
    const unsigned short* row = logits + (size_t)t * VP;
    int tg = target[t];
    float m = -1e30f, l = 0.0f, ztg = 0.0f;
    for (int i = threadIdx.x; i < VV; i += 256) {
        float z = bfb2f(row[i]);
        z = 30.0f * tanhf(z * (1.0f / 30.0f));
        if (i == tg) ztg = z;
        if (z > m) {
            l = l * __expf(m - z) + 1.0f;
            m = z;
        } else {
            l += __expf(z - m);
        }
    }
    __shared__ float ms[256], ls[256];
    __shared__ float zs;
    ms[threadIdx.x] = m;
    ls[threadIdx.x] = l;
    if (threadIdx.x == (tg & 255)) zs = ztg;
    for (int s2 = 128; s2 > 0; s2 >>= 1) {
        __syncthreads();
        if (threadIdx.x < s2) {
            float m2 = ms[threadIdx.x + s2], l2 = ls[threadIdx.x + s2];
            float m1 = ms[threadIdx.x], l1 = ls[threadIdx.x];
            float mm = fmaxf(m1, m2);
            ls[threadIdx.x] = l1 * __expf(m1 - mm) + l2 * __expf(m2 - mm);
            ms[threadIdx.x] = mm;
        }
    }
    __syncthreads();
    if (threadIdx.x == 0) {
        float lse = ms[0] + logf(ls[0]);
        float loss = lse - zs;
        bool masked = (tg == 16384) || (tg == 18433) || (tg == 18690);
        out[t] = masked ? 0.0f : loss;
    }
}

extern "C" void kernel_launch(void* const* d_in, const int* in_sizes, int n_in,
                              void* d_out, int out_size, void* d_ws, size_t ws_size,
                              hipStream_t stream)
{
    const int* idx = (const int*)d_in[0];
    const int* target = (const int*)d_in[1];
    const float* wte = (const float*)d_in[2];
    const float* lambdas = (const float*)d_in[3];
    const float* lamb = (const float*)d_in[4];
    const float* wq = (const float*)d_in[5];
    const float* wk = (const float*)d_in[6];
    const float* wv = (const float*)d_in[7];
    const float* wo = (const float*)d_in[8];
    const float* w1 = (const float*)d_in[9];
    const float* w2 = (const float*)d_in[10];
    const float* lm_head = (const float*)d_in[11];
    float* out = (float*)d_out;

    char* ws = (char*)d_ws;
    const size_t MB = (size_t)1 << 20;
    float* x            = (float*)(ws);
    unsigned short* x0  = (unsigned short*)(ws + 16 * MB);
    unsigned short* nrm = (unsigned short*)(ws + 24 * MB);
    unsigned short* qb  = (unsigned short*)(ws + 32 * MB);
    unsigned short* kb  = (unsigned short*)(ws + 40 * MB);
    unsigned short* vb  = (unsigned short*)(ws + 48 * MB);
    unsigned short* v1b = (unsigned short*)(ws + 56 * MB);
    unsigned short* yb  = (unsigned short*)(ws + 64 * MB);
    unsigned short* hid = (unsigned short*)(ws + 72 * MB);
    int* levels         = (int*)(ws + 104 * MB);
    unsigned short* logits = (unsigned short*)(ws + 105 * MB);

    embed_kernel<<<TT, 256, 0, stream>>>(idx, wte, x, x0, levels);

    for (int i = 0; i < NL; ++i) {
        mixnorm_kernel<<<TT, 256, 0, stream>>>(x, x0, lambdas + 2 * i, nrm);
        dim3 g8(8, 32);
        gemm_bt<0><<<g8, 256, 0, stream>>>(nrm, wq + (size_t)i * DM * DM, qb, nullptr, TT, DM, DM, DM);
        gemm_bt<0><<<g8, 256, 0, stream>>>(nrm, wk + (size_t)i * DM * DM, kb, nullptr, TT, DM, DM, DM);
        gemm_bt<0><<<g8, 256, 0, stream>>>(nrm, wv + (size_t)i * DM * DM, vb, nullptr, TT, DM, DM, DM);
        if (i == 0)
            vcopy_kernel<<<TT * DM / 1024, 256, 0, stream>>>(vb, v1b);
        else
            vmix_kernel<<<TT * DM / 1024, 256, 0, stream>>>(vb, v1b, lamb + i);
        rope_kernel<<<dim3(TT * NH / 4, 2), 256, 0, stream>>>(qb, kb);
        attn_kernel<<<dim3(BBATCH * NH, SS / 64), 128, 0, stream>>>(qb, kb, vb, yb, levels);
        gemm_bt<2><<<g8, 256, 0, stream>>>(yb, wo + (size_t)i * DM * DM, nullptr, x, TT, DM, DM, DM);
        norm_kernel<<<TT, 256, 0, stream>>>(x, nrm);
        gemm_bt<1><<<dim3(32, 32), 256, 0, stream>>>(nrm, w1 + (size_t)i * FFD * DM, hid, nullptr, TT, FFD, DM, FFD);
        gemm_bt<2><<<g8, 256, 0, stream>>>(hid, w2 + (size_t)i * DM * FFD, nullptr, x, TT, DM, FFD, DM);
    }

    norm_kernel<<<TT, 256, 0, stream>>>(x, nrm);
    gemm_bt<0><<<dim3(VP / 128, 32), 256, 0, stream>>>(nrm, lm_head, logits, nullptr, TT, VV, DM, VP);
    loss_kernel<<<TT, 256, 0, stream>>>(logits, target, out);
}

// Round 2
// 2730.218 us; speedup vs baseline: 1.8301x; 1.8301x over previous
//
#include <hip/hip_runtime.h>
#include <hip/hip_bf16.h>

#define TT 4096
#define SS 2048
#define BBATCH 2
#define DM 1024
#define NH 16
#define HD 64
#define FFD 4096
#define NL 4
#define VV 18691
#define VP 18816
#define APITCH 72

typedef __bf16 bf16x8 __attribute__((ext_vector_type(8)));
typedef float f32x4 __attribute__((ext_vector_type(4)));

__device__ __forceinline__ float bfb2f(unsigned short u) {
    union { unsigned int i; float f; } x;
    x.i = ((unsigned int)u) << 16;
    return x.f;
}
__device__ __forceinline__ unsigned short f2bfb(float f) {
    union { float f; unsigned int i; } x;
    x.f = f;
    unsigned int r = 0x7fffu + ((x.i >> 16) & 1u);
    x.i += r;
    return (unsigned short)(x.i >> 16);
}
__device__ __forceinline__ unsigned int pack2(float lo, float hi) {
    return (unsigned int)f2bfb(lo) | ((unsigned int)f2bfb(hi) << 16);
}

__device__ __forceinline__ float wave_sum(float v) {
#pragma unroll
    for (int o = 32; o; o >>= 1) v += __shfl_xor(v, o, 64);
    return v;
}

// 256-thread block sum
__device__ __forceinline__ float block_sum256(float v) {
    __shared__ float sb[4];
    v = wave_sum(v);
    int wid = threadIdx.x >> 6;
    if ((threadIdx.x & 63) == 0) sb[wid] = v;
    __syncthreads();
    float t = sb[0] + sb[1] + sb[2] + sb[3];
    __syncthreads();
    return t;
}

// x = rms_norm(wte[idx]); x0 = bf16(x); levels[t]
__global__ __launch_bounds__(256) void embed_kernel(
    const int* __restrict__ idx, const float* __restrict__ wte,
    float* __restrict__ x, unsigned short* __restrict__ x0, int* __restrict__ levels)
{
    int t = blockIdx.x;
    int id = idx[t];
    const float* row = wte + (size_t)id * DM;
    float4 v = *reinterpret_cast<const float4*>(row + threadIdx.x * 4);
    float ss = v.x * v.x + v.y * v.y + v.z * v.z + v.w * v.w;
    float tot = block_sum256(ss);
    float rs = rsqrtf(tot / (float)DM + 1e-6f);
    float4 o;
    o.x = v.x * rs; o.y = v.y * rs; o.z = v.z * rs; o.w = v.w * rs;
    size_t off = (size_t)t * DM + threadIdx.x * 4;
    *reinterpret_cast<float4*>(x + off) = o;
    ushort4 ub;
    ub.x = f2bfb(o.x); ub.y = f2bfb(o.y); ub.z = f2bfb(o.z); ub.w = f2bfb(o.w);
    *reinterpret_cast<ushort4*>(x0 + off) = ub;
    if (threadIdx.x == 0) levels[t] = (id >= 16385) + (id >= 18434);
}

// xr = l0*x + l1*x0 (written back to x); out = bf16(rms_norm(xr))
__global__ __launch_bounds__(256) void mixnorm_kernel(
    float* __restrict__ x, const unsigned short* __restrict__ x0,
    const float* __restrict__ lam2, unsigned short* __restrict__ out)
{
    int t = blockIdx.x;
    size_t off = (size_t)t * DM + threadIdx.x * 4;
    float4 xv = *reinterpret_cast<const float4*>(x + off);
    float l0 = lam2[0], l1 = lam2[1];
    ushort4 u = *reinterpret_cast<const ushort4*>(x0 + off);
    float4 r;
    r.x = l0 * xv.x + l1 * bfb2f(u.x);
    r.y = l0 * xv.y + l1 * bfb2f(u.y);
    r.z = l0 * xv.z + l1 * bfb2f(u.z);
    r.w = l0 * xv.w + l1 * bfb2f(u.w);
    float ss = r.x * r.x + r.y * r.y + r.z * r.z + r.w * r.w;
    float tot = block_sum256(ss);
    float rs = rsqrtf(tot / (float)DM + 1e-6f);
    *reinterpret_cast<float4*>(x + off) = r;
    ushort4 ob;
    ob.x = f2bfb(r.x * rs); ob.y = f2bfb(r.y * rs);
    ob.z = f2bfb(r.z * rs); ob.w = f2bfb(r.w * rs);
    *reinterpret_cast<ushort4*>(out + off) = ob;
}

// out = bf16(rms_norm(x)), x unmodified
__global__ __launch_bounds__(256) void norm_kernel(
    const float* __restrict__ x, unsigned short* __restrict__ out)
{
    int t = blockIdx.x;
    size_t off = (size_t)t * DM + threadIdx.x * 4;
    float4 r = *reinterpret_cast<const float4*>(x + off);
    float ss = r.x * r.x + r.y * r.y + r.z * r.z + r.w * r.w;
    float tot = block_sum256(ss);
    float rs = rsqrtf(tot / (float)DM + 1e-6f);
    ushort4 ob;
    ob.x = f2bfb(r.x * rs); ob.y = f2bfb(r.y * rs);
    ob.z = f2bfb(r.z * rs); ob.w = f2bfb(r.w * rs);
    *reinterpret_cast<ushort4*>(out + off) = ob;
}

// C = A(bf16 [M][K]) @ W^T, W = fp32 [N][K].
// EPI 0: C bf16.  EPI 1: C bf16 = relu(acc)^2.  EPI 2: Cf(fp32) += acc (in-place residual).
template <int EPI>
__global__ __launch_bounds__(256) void gemm_bt(
    const unsigned short* __restrict__ A, const float* __restrict__ Bw,
    unsigned short* __restrict__ Cb, float* __restrict__ Cf,
    int M, int N, int K, int ldC)
{
    __shared__ unsigned short As[128][40];
    __shared__ unsigned short Bs[128][40];
    int tid = threadIdx.x;
    int lane = tid & 63, wave = tid >> 6;
    int wr = wave >> 1, wc = wave & 1;
    int m0 = blockIdx.y * 128, n0 = blockIdx.x * 128;
    int sr = tid >> 2, scc = (tid & 3) * 8;

    const unsigned short* pA0 = A + (size_t)(m0 + sr) * K + scc;
    const unsigned short* pA1 = A + (size_t)(m0 + sr + 64) * K + scc;
    const float* pB0 = Bw + (size_t)(n0 + sr) * K + scc;
    const float* pB1 = Bw + (size_t)(n0 + sr + 64) * K + scc;
    bool ok0 = (n0 + sr) < N, ok1 = (n0 + sr + 64) < N;

    f32x4 acc[4][4];
#pragma unroll
    for (int m = 0; m < 4; ++m)
#pragma unroll
        for (int n = 0; n < 4; ++n) acc[m][n] = 0.0f;

    int fr = lane & 15, fchunk = (lane >> 4) * 8;

    for (int kt = 0; kt < K; kt += 32) {
        int4 av0 = *reinterpret_cast<const int4*>(pA0 + kt);
        int4 av1 = *reinterpret_cast<const int4*>(pA1 + kt);
        float4 b00 = {0, 0, 0, 0}, b01 = {0, 0, 0, 0}, b10 = {0, 0, 0, 0}, b11 = {0, 0, 0, 0};
        if (ok0) { b00 = *reinterpret_cast<const float4*>(pB0 + kt); b01 = *reinterpret_cast<const float4*>(pB0 + kt + 4); }
        if (ok1) { b10 = *reinterpret_cast<const float4*>(pB1 + kt); b11 = *reinterpret_cast<const float4*>(pB1 + kt + 4); }
        __syncthreads();
        *reinterpret_cast<int4*>(&As[sr][scc]) = av0;
        *reinterpret_cast<int4*>(&As[sr + 64][scc]) = av1;
        uint4 bp0, bp1;
        bp0.x = pack2(b00.x, b00.y); bp0.y = pack2(b00.z, b00.w);
        bp0.z = pack2(b01.x, b01.y); bp0.w = pack2(b01.z, b01.w);
        bp1.x = pack2(b10.x, b10.y); bp1.y = pack2(b10.z, b10.w);
        bp1.z = pack2(b11.x, b11.y); bp1.w = pack2(b11.z, b11.w);
        *reinterpret_cast<uint4*>(&Bs[sr][scc]) = bp0;
        *reinterpret_cast<uint4*>(&Bs[sr + 64][scc]) = bp1;
        __syncthreads();
        bf16x8 af[4], bfv[4];
#pragma unroll
        for (int m = 0; m < 4; ++m)
            af[m] = *reinterpret_cast<const bf16x8*>(&As[wr * 64 + m * 16 + fr][fchunk]);
#pragma unroll
        for (int n = 0; n < 4; ++n)
            bfv[n] = *reinterpret_cast<const bf16x8*>(&Bs[wc * 64 + n * 16 + fr][fchunk]);
#pragma unroll
        for (int m = 0; m < 4; ++m)
#pragma unroll
            for (int n = 0; n < 4; ++n)
                acc[m][n] = __builtin_amdgcn_mfma_f32_16x16x32_bf16(af[m], bfv[n], acc[m][n], 0, 0, 0);
    }

    int rb = m0 + wr * 64 + (lane >> 4) * 4;
    int cb = n0 + wc * 64 + (lane & 15);
#pragma unroll
    for (int n = 0; n < 4; ++n) {
        int gc = cb + n * 16;
        if (gc >= N) continue;
#pragma unroll
        for (int m = 0; m < 4; ++m) {
#pragma unroll
            for (int j = 0; j < 4; ++j) {
                int gr = rb + m * 16 + j;
                float val = acc[m][n][j];
                if constexpr (EPI == 0) {
                    Cb[(size_t)gr * ldC + gc] = f2bfb(val);
                } else if constexpr (EPI == 1) {
                    float rl = fmaxf(val, 0.0f);
                    Cb[(size_t)gr * ldC + gc] = f2bfb(rl * rl);
                } else {
                    size_t o = (size_t)gr * ldC + gc;
                    Cf[o] = Cf[o] + val;
                }
            }
        }
    }
}

__global__ void vcopy_kernel(const unsigned short* __restrict__ v, unsigned short* __restrict__ v1)
{
    int i = blockIdx.x * 256 + threadIdx.x;
    reinterpret_cast<ushort4*>(v1)[i] = reinterpret_cast<const ushort4*>(v)[i];
}

__global__ void vmix_kernel(unsigned short* __restrict__ v, const unsigned short* __restrict__ v1,
                            const float* __restrict__ lamb)
{
    int i = blockIdx.x * 256 + threadIdx.x;
    float la = *lamb;
    ushort4 a = reinterpret_cast<const ushort4*>(v)[i];
    ushort4 b = reinterpret_cast<const ushort4*>(v1)[i];
    ushort4 o;
    o.x = f2bfb((1.0f - la) * bfb2f(a.x) + la * bfb2f(b.x));
    o.y = f2bfb((1.0f - la) * bfb2f(a.y) + la * bfb2f(b.y));
    o.z = f2bfb((1.0f - la) * bfb2f(a.z) + la * bfb2f(b.z));
    o.w = f2bfb((1.0f - la) * bfb2f(a.w) + la * bfb2f(b.w));
    reinterpret_cast<ushort4*>(v)[i] = o;
}

// per-(t,h) head rms_norm + rotary; applied in-place to q (blockIdx.y==0) or k (==1)
__global__ __launch_bounds__(256) void rope_kernel(unsigned short* __restrict__ q,
                                                   unsigned short* __restrict__ k)
{
    int wid = threadIdx.x >> 6, lane = threadIdx.x & 63;
    int id = blockIdx.x * 4 + wid; // t*NH + h
    unsigned short* p = blockIdx.y ? k : q;
    int t = id >> 4, h = id & 15;
    int s = t & (SS - 1);
    size_t off = (size_t)t * DM + h * HD + lane;
    float val = bfb2f(p[off]);
    float ss = wave_sum(val * val);
    float rs = rsqrtf(ss / (float)HD + 1e-6f);
    float nv = val * rs;
    float other = __shfl_xor(nv, 32, 64);
    int j = lane & 31;
    // inv_freq = 10000^(-j/32) = exp2(-j * log2(10000)/32)
    float invf = exp2f(-(float)j * 0.41524101186092025f);
    float fr = (float)s * invf;
    float sn, cs;
    sincosf(fr, &sn, &cs);
    float outv = (lane < 32) ? (nv * cs + other * sn) : (nv * cs - other * sn);
    p[off] = f2bfb(outv);
}

// MFMA flash attention. 256 threads / 4 waves; block = 64 queries of one (b,h).
// Wave w owns query rows [w*16, w*16+16). K-tiles of 64 keys.
__global__ __launch_bounds__(256) void attn_mfma_kernel(
    const unsigned short* __restrict__ q, const unsigned short* __restrict__ k,
    const unsigned short* __restrict__ v, unsigned short* __restrict__ y,
    const int* __restrict__ levels)
{
    __shared__ unsigned short Qs[64][APITCH];
    __shared__ unsigned short Ks[64][APITCH];
    __shared__ unsigned short Vt[64][APITCH]; // Vt[d][kk] = V[kk][d]
    __shared__ unsigned short Ps[64][APITCH]; // wave-private rows
    __shared__ int lvlS[64];

    int bh = blockIdx.x;
    int b = bh >> 4, h = bh & 15;
    int q0 = blockIdx.y * 64;
    size_t base = (size_t)b * SS * DM + h * HD;
    int tid = threadIdx.x;
    int lane = tid & 63, w = tid >> 6;
    int srow = tid >> 2, sc = tid & 3;

    // stage Q (rows are wave-local: srow in [w*16, w*16+16))
    {
        const unsigned short* src = q + base + (size_t)(q0 + srow) * DM;
        *reinterpret_cast<uint4*>(&Qs[srow][sc * 8]) = *reinterpret_cast<const uint4*>(src + sc * 8);
        *reinterpret_cast<uint4*>(&Qs[srow][(sc + 4) * 8]) = *reinterpret_cast<const uint4*>(src + (sc + 4) * 8);
    }
    __syncthreads();

    int fr = lane & 15, fc = (lane >> 4) * 8;
    int rj = (lane >> 4) * 4; // row base within wave's 16 rows for C-layout

    bf16x8 qa[2];
    qa[0] = *reinterpret_cast<const bf16x8*>(&Qs[w * 16 + fr][fc]);
    qa[1] = *reinterpret_cast<const bf16x8*>(&Qs[w * 16 + fr][32 + fc]);

    float mreg[4], lreg[4];
    f32x4 yacc[4];
#pragma unroll
    for (int j = 0; j < 4; ++j) { mreg[j] = -1e30f; lreg[j] = 0.0f; yacc[j] = 0.0f; }

    int ntile = blockIdx.y + 1;
    for (int kt = 0; kt < ntile; ++kt) {
        int k0 = kt * 64;
        __syncthreads(); // previous tile fully consumed
        {
            size_t goff = base + (size_t)(k0 + srow) * DM;
            uint4 kv0 = *reinterpret_cast<const uint4*>(k + goff + sc * 8);
            uint4 kv1 = *reinterpret_cast<const uint4*>(k + goff + (sc + 4) * 8);
            *reinterpret_cast<uint4*>(&Ks[srow][sc * 8]) = kv0;
            *reinterpret_cast<uint4*>(&Ks[srow][(sc + 4) * 8]) = kv1;
            uint4 vv0 = *reinterpret_cast<const uint4*>(v + goff + sc * 8);
            uint4 vv1 = *reinterpret_cast<const uint4*>(v + goff + (sc + 4) * 8);
            const unsigned short* e0 = reinterpret_cast<const unsigned short*>(&vv0);
            const unsigned short* e1 = reinterpret_cast<const unsigned short*>(&vv1);
#pragma unroll
            for (int i = 0; i < 8; ++i) Vt[sc * 8 + i][srow] = e0[i];
#pragma unroll
            for (int i = 0; i < 8; ++i) Vt[(sc + 4) * 8 + i][srow] = e1[i];
            if (tid < 64) lvlS[tid] = levels[b * SS + k0 + tid];
        }
        __syncthreads();

        // QK^T: S[16q x 64k] per wave
        f32x4 sacc[4];
#pragma unroll
        for (int n = 0; n < 4; ++n) {
            bf16x8 kb0 = *reinterpret_cast<const bf16x8*>(&Ks[n * 16 + fr][fc]);
            bf16x8 kb1 = *reinterpret_cast<const bf16x8*>(&Ks[n * 16 + fr][32 + fc]);
            f32x4 a = {0.0f, 0.0f, 0.0f, 0.0f};
            a = __builtin_amdgcn_mfma_f32_16x16x32_bf16(qa[0], kb0, a, 0, 0, 0);
            a = __builtin_amdgcn_mfma_f32_16x16x32_bf16(qa[1], kb1, a, 0, 0, 0);
            sacc[n] = a;
        }

        // mask + online softmax
        float sm[4][4]; // [n][j]
        float cm[4] = {-1e30f, -1e30f, -1e30f, -1e30f};
#pragma unroll
        for (int n = 0; n < 4; ++n) {
            int kg = k0 + n * 16 + fr;
            int L = lvlS[n * 16 + fr];
#pragma unroll
            for (int j = 0; j < 4; ++j) {
                int qg = q0 + w * 16 + rj + j;
                bool valid = (kg <= qg) && (L > 0 || (qg - kg) <= 256);
                float s = valid ? sacc[n][j] * 0.125f : -1e30f;
                sm[n][j] = s;
                cm[j] = fmaxf(cm[j], s);
            }
        }
#pragma unroll
        for (int j = 0; j < 4; ++j) {
            cm[j] = fmaxf(cm[j], __shfl_xor(cm[j], 1, 64));
            cm[j] = fmaxf(cm[j], __shfl_xor(cm[j], 2, 64));
            cm[j] = fmaxf(cm[j], __shfl_xor(cm[j], 4, 64));
            cm[j] = fmaxf(cm[j], __shfl_xor(cm[j], 8, 64));
        }
        float sj[4], ps[4];
#pragma unroll
        for (int j = 0; j < 4; ++j) {
            float nm = fmaxf(mreg[j], cm[j]);
            sj[j] = __expf(mreg[j] - nm);
            mreg[j] = nm;
            ps[j] = 0.0f;
        }
#pragma unroll
        for (int n = 0; n < 4; ++n) {
#pragma unroll
            for (int j = 0; j < 4; ++j) {
                float p = (sm[n][j] > -1e29f) ? __expf(sm[n][j] - mreg[j]) : 0.0f;
                Ps[w * 16 + rj + j][n * 16 + fr] = f2bfb(p);
                ps[j] += p;
            }
        }
#pragma unroll
        for (int j = 0; j < 4; ++j) {
            float t = ps[j];
            t += __shfl_xor(t, 1, 64); t += __shfl_xor(t, 2, 64);
            t += __shfl_xor(t, 4, 64); t += __shfl_xor(t, 8, 64);
            lreg[j] = lreg[j] * sj[j] + t;
        }
#pragma unroll
        for (int n = 0; n < 4; ++n)
#pragma unroll
            for (int j = 0; j < 4; ++j) yacc[n][j] *= sj[j];

        // PV: A = Ps rows (wave-private), B = Vt
        bf16x8 pa0 = *reinterpret_cast<const bf16x8*>(&Ps[w * 16 + fr][fc]);
        bf16x8 pa1 = *reinterpret_cast<const bf16x8*>(&Ps[w * 16 + fr][32 + fc]);
#pragma unroll
        for (int n = 0; n < 4; ++n) {
            bf16x8 vb0 = *reinterpret_cast<const bf16x8*>(&Vt[n * 16 + fr][fc]);
            bf16x8 vb1 = *reinterpret_cast<const bf16x8*>(&Vt[n * 16 + fr][32 + fc]);
            yacc[n] = __builtin_amdgcn_mfma_f32_16x16x32_bf16(pa0, vb0, yacc[n], 0, 0, 0);
            yacc[n] = __builtin_amdgcn_mfma_f32_16x16x32_bf16(pa1, vb1, yacc[n], 0, 0, 0);
        }
    }

    float inv[4];
#pragma unroll
    for (int j = 0; j < 4; ++j) inv[j] = 1.0f / lreg[j];
#pragma unroll
    for (int n = 0; n < 4; ++n) {
#pragma unroll
        for (int j = 0; j < 4; ++j) {
            int qg = q0 + w * 16 + rj + j;
            y[base + (size_t)qg * DM + n * 16 + fr] = f2bfb(yacc[n][j] * inv[j]);
        }
    }
}

// per-token: softcap + logsumexp + NLL
__global__ __launch_bounds__(256) void loss_kernel(
    const unsigned short* __restrict__ logits, const int* __restrict__ target,
    float* __restrict__ out)
{
    int t = blockIdx.x;
    const unsigned short* row = logits + (size_t)t * VP;
    int tg = target[t];
    float m = -1e30f, l = 0.0f, ztg = 0.0f;
    for (int i = threadIdx.x; i < VV; i += 256) {
        float z = bfb2f(row[i]);
        z = 30.0f * tanhf(z * (1.0f / 30.0f));
        if (i == tg) ztg = z;
        if (z > m) {
            l = l * __expf(m - z) + 1.0f;
            m = z;
        } else {
            l += __expf(z - m);
        }
    }
    __shared__ float ms[256], ls[256];
    __shared__ float zs;
    ms[threadIdx.x] = m;
    ls[threadIdx.x] = l;
    if (threadIdx.x == (tg & 255)) zs = ztg;
    for (int s2 = 128; s2 > 0; s2 >>= 1) {
        __syncthreads();
        if (threadIdx.x < s2) {
            float m2 = ms[threadIdx.x + s2], l2 = ls[threadIdx.x + s2];
            float m1 = ms[threadIdx.x], l1 = ls[threadIdx.x];
            float mm = fmaxf(m1, m2);
            ls[threadIdx.x] = l1 * __expf(m1 - mm) + l2 * __expf(m2 - mm);
            ms[threadIdx.x] = mm;
        }
    }
    __syncthreads();
    if (threadIdx.x == 0) {
        float lse = ms[0] + logf(ls[0]);
        float loss = lse - zs;
        bool masked = (tg == 16384) || (tg == 18433) || (tg == 18690);
        out[t] = masked ? 0.0f : loss;
    }
}

extern "C" void kernel_launch(void* const* d_in, const int* in_sizes, int n_in,
                              void* d_out, int out_size, void* d_ws, size_t ws_size,
                              hipStream_t stream)
{
    const int* idx = (const int*)d_in[0];
    const int* target = (const int*)d_in[1];
    const float* wte = (const float*)d_in[2];
    const float* lambdas = (const float*)d_in[3];
    const float* lamb = (const float*)d_in[4];
    const float* wq = (const float*)d_in[5];
    const float* wk = (const float*)d_in[6];
    const float* wv = (const float*)d_in[7];
    const float* wo = (const float*)d_in[8];
    const float* w1 = (const float*)d_in[9];
    const float* w2 = (const float*)d_in[10];
    const float* lm_head = (const float*)d_in[11];
    float* out = (float*)d_out;

    char* ws = (char*)d_ws;
    const size_t MB = (size_t)1 << 20;
    float* x            = (float*)(ws);
    unsigned short* x0  = (unsigned short*)(ws + 16 * MB);
    unsigned short* nrm = (unsigned short*)(ws + 24 * MB);
    unsigned short* qb  = (unsigned short*)(ws + 32 * MB);
    unsigned short* kb  = (unsigned short*)(ws + 40 * MB);
    unsigned short* vb  = (unsigned short*)(ws + 48 * MB);
    unsigned short* v1b = (unsigned short*)(ws + 56 * MB);
    unsigned short* yb  = (unsigned short*)(ws + 64 * MB);
    unsigned short* hid = (unsigned short*)(ws + 72 * MB);
    int* levels         = (int*)(ws + 104 * MB);
    unsigned short* logits = (unsigned short*)(ws + 105 * MB);

    embed_kernel<<<TT, 256, 0, stream>>>(idx, wte, x, x0, levels);

    for (int i = 0; i < NL; ++i) {
        mixnorm_kernel<<<TT, 256, 0, stream>>>(x, x0, lambdas + 2 * i, nrm);
        dim3 g8(8, 32);
        gemm_bt<0><<<g8, 256, 0, stream>>>(nrm, wq + (size_t)i * DM * DM, qb, nullptr, TT, DM, DM, DM);
        gemm_bt<0><<<g8, 256, 0, stream>>>(nrm, wk + (size_t)i * DM * DM, kb, nullptr, TT, DM, DM, DM);
        gemm_bt<0><<<g8, 256, 0, stream>>>(nrm, wv + (size_t)i * DM * DM, vb, nullptr, TT, DM, DM, DM);
        if (i == 0)
            vcopy_kernel<<<TT * DM / 1024, 256, 0, stream>>>(vb, v1b);
        else
            vmix_kernel<<<TT * DM / 1024, 256, 0, stream>>>(vb, v1b, lamb + i);
        rope_kernel<<<dim3(TT * NH / 4, 2), 256, 0, stream>>>(qb, kb);
        attn_mfma_kernel<<<dim3(BBATCH * NH, SS / 64), 256, 0, stream>>>(qb, kb, vb, yb, levels);
        gemm_bt<2><<<g8, 256, 0, stream>>>(yb, wo + (size_t)i * DM * DM, nullptr, x, TT, DM, DM, DM);
        norm_kernel<<<TT, 256, 0, stream>>>(x, nrm);
        gemm_bt<1><<<dim3(32, 32), 256, 0, stream>>>(nrm, w1 + (size_t)i * FFD * DM, hid, nullptr, TT, FFD, DM, FFD);
        gemm_bt<2><<<g8, 256, 0, stream>>>(hid, w2 + (size_t)i * DM * FFD, nullptr, x, TT, DM, FFD, DM);
    }

    norm_kernel<<<TT, 256, 0, stream>>>(x, nrm);
    gemm_bt<0><<<dim3(VP / 128, 32), 256, 0, stream>>>(nrm, lm_head, logits, nullptr, TT, VV, DM, VP);
    loss_kernel<<<TT, 256, 0, stream>>>(logits, target, out);
}

// Round 3
// 2729.317 us; speedup vs baseline: 1.8307x; 1.0003x over previous
//
#include <hip/hip_runtime.h>
#include <hip/hip_bf16.h>

#define TT 4096
#define SS 2048
#define BBATCH 2
#define DM 1024
#define NH 16
#define HD 64
#define FFD 4096
#define NL 4
#define VV 18691
#define VP 18816
#define APITCH 72

typedef __bf16 bf16x8 __attribute__((ext_vector_type(8)));
typedef float f32x4 __attribute__((ext_vector_type(4)));
typedef const __attribute__((address_space(1))) void* gas_t;
typedef __attribute__((address_space(3))) void* las_t;

__device__ __forceinline__ float bfb2f(unsigned short u) {
    union { unsigned int i; float f; } x;
    x.i = ((unsigned int)u) << 16;
    return x.f;
}
__device__ __forceinline__ unsigned short f2bfb(float f) {
    union { float f; unsigned int i; } x;
    x.f = f;
    unsigned int r = 0x7fffu + ((x.i >> 16) & 1u);
    x.i += r;
    return (unsigned short)(x.i >> 16);
}
__device__ __forceinline__ unsigned int pack2(float lo, float hi) {
    return (unsigned int)f2bfb(lo) | ((unsigned int)f2bfb(hi) << 16);
}

__device__ __forceinline__ float wave_sum(float v) {
#pragma unroll
    for (int o = 32; o; o >>= 1) v += __shfl_xor(v, o, 64);
    return v;
}

__device__ __forceinline__ float block_sum256(float v) {
    __shared__ float sb[4];
    v = wave_sum(v);
    int wid = threadIdx.x >> 6;
    if ((threadIdx.x & 63) == 0) sb[wid] = v;
    __syncthreads();
    float t = sb[0] + sb[1] + sb[2] + sb[3];
    __syncthreads();
    return t;
}

// ---- weight fp32 -> bf16 conversion ----
__global__ __launch_bounds__(256) void cvtw_kernel(const float* __restrict__ src,
                                                   unsigned short* __restrict__ dst, int n)
{
    int i = (blockIdx.x * 256 + threadIdx.x) * 4;
    if (i >= n) return;
    float4 f = *reinterpret_cast<const float4*>(src + i);
    ushort4 u;
    u.x = f2bfb(f.x); u.y = f2bfb(f.y); u.z = f2bfb(f.z); u.w = f2bfb(f.w);
    *reinterpret_cast<ushort4*>(dst + i) = u;
}

__global__ __launch_bounds__(256) void cvtpad_kernel(const float* __restrict__ src,
                                                     unsigned short* __restrict__ dst,
                                                     int nreal, int ntot)
{
    int i = (blockIdx.x * 256 + threadIdx.x) * 4;
    if (i >= ntot) return;
    ushort4 u = {0, 0, 0, 0};
    if (i < nreal) {
        float4 f = *reinterpret_cast<const float4*>(src + i);
        u.x = f2bfb(f.x); u.y = f2bfb(f.y); u.z = f2bfb(f.z); u.w = f2bfb(f.w);
    }
    *reinterpret_cast<ushort4*>(dst + i) = u;
}

// x = rms_norm(wte[idx]); x0 = bf16(x); levels[t]
__global__ __launch_bounds__(256) void embed_kernel(
    const int* __restrict__ idx, const float* __restrict__ wte,
    float* __restrict__ x, unsigned short* __restrict__ x0, int* __restrict__ levels)
{
    int t = blockIdx.x;
    int id = idx[t];
    const float* row = wte + (size_t)id * DM;
    float4 v = *reinterpret_cast<const float4*>(row + threadIdx.x * 4);
    float ss = v.x * v.x + v.y * v.y + v.z * v.z + v.w * v.w;
    float tot = block_sum256(ss);
    float rs = rsqrtf(tot / (float)DM + 1e-6f);
    float4 o;
    o.x = v.x * rs; o.y = v.y * rs; o.z = v.z * rs; o.w = v.w * rs;
    size_t off = (size_t)t * DM + threadIdx.x * 4;
    *reinterpret_cast<float4*>(x + off) = o;
    ushort4 ub;
    ub.x = f2bfb(o.x); ub.y = f2bfb(o.y); ub.z = f2bfb(o.z); ub.w = f2bfb(o.w);
    *reinterpret_cast<ushort4*>(x0 + off) = ub;
    if (threadIdx.x == 0) levels[t] = (id >= 16385) + (id >= 18434);
}

// xr = l0*x + l1*x0 (written back to x); out = bf16(rms_norm(xr))
__global__ __launch_bounds__(256) void mixnorm_kernel(
    float* __restrict__ x, const unsigned short* __restrict__ x0,
    const float* __restrict__ lam2, unsigned short* __restrict__ out)
{
    int t = blockIdx.x;
    size_t off = (size_t)t * DM + threadIdx.x * 4;
    float4 xv = *reinterpret_cast<const float4*>(x + off);
    float l0 = lam2[0], l1 = lam2[1];
    ushort4 u = *reinterpret_cast<const ushort4*>(x0 + off);
    float4 r;
    r.x = l0 * xv.x + l1 * bfb2f(u.x);
    r.y = l0 * xv.y + l1 * bfb2f(u.y);
    r.z = l0 * xv.z + l1 * bfb2f(u.z);
    r.w = l0 * xv.w + l1 * bfb2f(u.w);
    float ss = r.x * r.x + r.y * r.y + r.z * r.z + r.w * r.w;
    float tot = block_sum256(ss);
    float rs = rsqrtf(tot / (float)DM + 1e-6f);
    *reinterpret_cast<float4*>(x + off) = r;
    ushort4 ob;
    ob.x = f2bfb(r.x * rs); ob.y = f2bfb(r.y * rs);
    ob.z = f2bfb(r.z * rs); ob.w = f2bfb(r.w * rs);
    *reinterpret_cast<ushort4*>(out + off) = ob;
}

// out = bf16(rms_norm(x)), x unmodified
__global__ __launch_bounds__(256) void norm_kernel(
    const float* __restrict__ x, unsigned short* __restrict__ out)
{
    int t = blockIdx.x;
    size_t off = (size_t)t * DM + threadIdx.x * 4;
    float4 r = *reinterpret_cast<const float4*>(x + off);
    float ss = r.x * r.x + r.y * r.y + r.z * r.z + r.w * r.w;
    float tot = block_sum256(ss);
    float rs = rsqrtf(tot / (float)DM + 1e-6f);
    ushort4 ob;
    ob.x = f2bfb(r.x * rs); ob.y = f2bfb(r.y * rs);
    ob.z = f2bfb(r.z * rs); ob.w = f2bfb(r.w * rs);
    *reinterpret_cast<ushort4*>(out + off) = ob;
}

// ---------- bf16-weight GEMM, m97 structure ----------
// C[M=4096][N] = A(bf16 [M][K]) @ W^T, W bf16 [N][K], N multiple of 128, K multiple of 64.
// 128x128 tile, BK=64, global_load_lds w=16, T2 swizzle (inverse-swizzled source + swizzled read).
// EPI 0: C bf16. EPI 1: C bf16 = relu(acc)^2. EPI 2: Cf fp32 += acc.
template <int EPI>
__global__ __launch_bounds__(256) void gemm_bb(
    const unsigned short* __restrict__ A, const unsigned short* __restrict__ Bw,
    unsigned short* __restrict__ Cb, float* __restrict__ Cf,
    int NX, int K, int ldC)
{
    __shared__ unsigned short As[128 * 64];
    __shared__ unsigned short Bs[128 * 64];

    // bijective XCD swizzle (m204), then row-major tile decode: consecutive wg share the A panel
    int nwg = gridDim.x;
    int orig = blockIdx.x;
    int qq = nwg >> 3, rr = nwg & 7;
    int xcd = orig & 7, rem = orig >> 3;
    int wg = (xcd < rr ? xcd * (qq + 1) : rr * (qq + 1) + (xcd - rr) * qq) + rem;
    int bx = wg % NX, by = wg / NX;
    int m0 = by * 128, n0 = bx * 128;

    int tid = threadIdx.x, lane = tid & 63, w = tid >> 6;
    int wr = w >> 1, wc = w & 1;
    int rsub = lane >> 3, sl = lane & 7;
    int ssrc = sl ^ rsub;           // inverse-swizzled source slot
    int fr = lane & 15, fh = lane >> 4;

    size_t arow[4], brow[4];
#pragma unroll
    for (int i = 0; i < 4; ++i) {
        int c = 4 * w + i;
        arow[i] = (size_t)(m0 + 8 * c + rsub) * K + ssrc * 8;
        brow[i] = (size_t)(n0 + 8 * c + rsub) * K + ssrc * 8;
    }

    f32x4 acc[4][4];
#pragma unroll
    for (int m = 0; m < 4; ++m)
#pragma unroll
        for (int n = 0; n < 4; ++n) acc[m][n] = 0.0f;

    int NT = K >> 6;
    for (int kt = 0; kt < NT; ++kt) {
        int kb = kt * 64;
#pragma unroll
        for (int i = 0; i < 4; ++i) {
            __builtin_amdgcn_global_load_lds((gas_t)(const void*)(A + arow[i] + kb),
                                             (las_t)(void*)(&As[(4 * w + i) * 512]), 16, 0, 0);
            __builtin_amdgcn_global_load_lds((gas_t)(const void*)(Bw + brow[i] + kb),
                                             (las_t)(void*)(&Bs[(4 * w + i) * 512]), 16, 0, 0);
        }
        __syncthreads();
#pragma unroll
        for (int kk = 0; kk < 2; ++kk) {
            int slot = kk * 4 + fh;
            bf16x8 af[4], bfv[4];
#pragma unroll
            for (int m = 0; m < 4; ++m) {
                int row = wr * 64 + m * 16 + fr;
                af[m] = *reinterpret_cast<const bf16x8*>(&As[row * 64 + ((slot ^ (row & 7)) << 3)]);
            }
#pragma unroll
            for (int n = 0; n < 4; ++n) {
                int row = wc * 64 + n * 16 + fr;
                bfv[n] = *reinterpret_cast<const bf16x8*>(&Bs[row * 64 + ((slot ^ (row & 7)) << 3)]);
            }
#pragma unroll
            for (int m = 0; m < 4; ++m)
#pragma unroll
                for (int n = 0; n < 4; ++n)
                    acc[m][n] = __builtin_amdgcn_mfma_f32_16x16x32_bf16(af[m], bfv[n], acc[m][n], 0, 0, 0);
        }
        __syncthreads();
    }

    int rb = m0 + wr * 64 + fh * 4;
    int cb = n0 + wc * 64 + fr;
#pragma unroll
    for (int n = 0; n < 4; ++n) {
        int gc = cb + n * 16;
#pragma unroll
        for (int m = 0; m < 4; ++m) {
#pragma unroll
            for (int j = 0; j < 4; ++j) {
                int gr = rb + m * 16 + j;
                float val = acc[m][n][j];
                if constexpr (EPI == 0) {
                    Cb[(size_t)gr * ldC + gc] = f2bfb(val);
                } else if constexpr (EPI == 1) {
                    float rl = fmaxf(val, 0.0f);
                    Cb[(size_t)gr * ldC + gc] = f2bfb(rl * rl);
                } else {
                    size_t o = (size_t)gr * ldC + gc;
                    Cf[o] = Cf[o] + val;
                }
            }
        }
    }
}

// ---------- fp32-weight GEMM (fallback when ws too small for converted weights) ----------
template <int EPI>
__global__ __launch_bounds__(256) void gemm_bt(
    const unsigned short* __restrict__ A, const float* __restrict__ Bw,
    unsigned short* __restrict__ Cb, float* __restrict__ Cf,
    int M, int N, int K, int ldC)
{
    __shared__ unsigned short As[128][40];
    __shared__ unsigned short Bs[128][40];
    int tid = threadIdx.x;
    int lane = tid & 63, wave = tid >> 6;
    int wr = wave >> 1, wc = wave & 1;
    int m0 = blockIdx.y * 128, n0 = blockIdx.x * 128;
    int sr = tid >> 2, scc = (tid & 3) * 8;

    const unsigned short* pA0 = A + (size_t)(m0 + sr) * K + scc;
    const unsigned short* pA1 = A + (size_t)(m0 + sr + 64) * K + scc;
    const float* pB0 = Bw + (size_t)(n0 + sr) * K + scc;
    const float* pB1 = Bw + (size_t)(n0 + sr + 64) * K + scc;
    bool ok0 = (n0 + sr) < N, ok1 = (n0 + sr + 64) < N;

    f32x4 acc[4][4];
#pragma unroll
    for (int m = 0; m < 4; ++m)
#pragma unroll
        for (int n = 0; n < 4; ++n) acc[m][n] = 0.0f;

    int fr = lane & 15, fchunk = (lane >> 4) * 8;

    for (int kt = 0; kt < K; kt += 32) {
        int4 av0 = *reinterpret_cast<const int4*>(pA0 + kt);
        int4 av1 = *reinterpret_cast<const int4*>(pA1 + kt);
        float4 b00 = {0, 0, 0, 0}, b01 = {0, 0, 0, 0}, b10 = {0, 0, 0, 0}, b11 = {0, 0, 0, 0};
        if (ok0) { b00 = *reinterpret_cast<const float4*>(pB0 + kt); b01 = *reinterpret_cast<const float4*>(pB0 + kt + 4); }
        if (ok1) { b10 = *reinterpret_cast<const float4*>(pB1 + kt); b11 = *reinterpret_cast<const float4*>(pB1 + kt + 4); }
        __syncthreads();
        *reinterpret_cast<int4*>(&As[sr][scc]) = av0;
        *reinterpret_cast<int4*>(&As[sr + 64][scc]) = av1;
        uint4 bp0, bp1;
        bp0.x = pack2(b00.x, b00.y); bp0.y = pack2(b00.z, b00.w);
        bp0.z = pack2(b01.x, b01.y); bp0.w = pack2(b01.z, b01.w);
        bp1.x = pack2(b10.x, b10.y); bp1.y = pack2(b10.z, b10.w);
        bp1.z = pack2(b11.x, b11.y); bp1.w = pack2(b11.z, b11.w);
        *reinterpret_cast<uint4*>(&Bs[sr][scc]) = bp0;
        *reinterpret_cast<uint4*>(&Bs[sr + 64][scc]) = bp1;
        __syncthreads();
        bf16x8 af[4], bfv[4];
#pragma unroll
        for (int m = 0; m < 4; ++m)
            af[m] = *reinterpret_cast<const bf16x8*>(&As[wr * 64 + m * 16 + fr][fchunk]);
#pragma unroll
        for (int n = 0; n < 4; ++n)
            bfv[n] = *reinterpret_cast<const bf16x8*>(&Bs[wc * 64 + n * 16 + fr][fchunk]);
#pragma unroll
        for (int m = 0; m < 4; ++m)
#pragma unroll
            for (int n = 0; n < 4; ++n)
                acc[m][n] = __builtin_amdgcn_mfma_f32_16x16x32_bf16(af[m], bfv[n], acc[m][n], 0, 0, 0);
    }

    int rb = m0 + wr * 64 + (lane >> 4) * 4;
    int cb = n0 + wc * 64 + (lane & 15);
#pragma unroll
    for (int n = 0; n < 4; ++n) {
        int gc = cb + n * 16;
        if (gc >= N) continue;
#pragma unroll
        for (int m = 0; m < 4; ++m) {
#pragma unroll
            for (int j = 0; j < 4; ++j) {
                int gr = rb + m * 16 + j;
                float val = acc[m][n][j];
                if constexpr (EPI == 0) {
                    Cb[(size_t)gr * ldC + gc] = f2bfb(val);
                } else if constexpr (EPI == 1) {
                    float rl = fmaxf(val, 0.0f);
                    Cb[(size_t)gr * ldC + gc] = f2bfb(rl * rl);
                } else {
                    size_t o = (size_t)gr * ldC + gc;
                    Cf[o] = Cf[o] + val;
                }
            }
        }
    }
}

__global__ void vcopy_kernel(const unsigned short* __restrict__ v, unsigned short* __restrict__ v1)
{
    int i = blockIdx.x * 256 + threadIdx.x;
    reinterpret_cast<ushort4*>(v1)[i] = reinterpret_cast<const ushort4*>(v)[i];
}

__global__ void vmix_kernel(unsigned short* __restrict__ v, const unsigned short* __restrict__ v1,
                            const float* __restrict__ lamb)
{
    int i = blockIdx.x * 256 + threadIdx.x;
    float la = *lamb;
    ushort4 a = reinterpret_cast<const ushort4*>(v)[i];
    ushort4 b = reinterpret_cast<const ushort4*>(v1)[i];
    ushort4 o;
    o.x = f2bfb((1.0f - la) * bfb2f(a.x) + la * bfb2f(b.x));
    o.y = f2bfb((1.0f - la) * bfb2f(a.y) + la * bfb2f(b.y));
    o.z = f2bfb((1.0f - la) * bfb2f(a.z) + la * bfb2f(b.z));
    o.w = f2bfb((1.0f - la) * bfb2f(a.w) + la * bfb2f(b.w));
    reinterpret_cast<ushort4*>(v)[i] = o;
}

// per-(t,h) head rms_norm + rotary; applied in-place to q (blockIdx.y==0) or k (==1)
__global__ __launch_bounds__(256) void rope_kernel(unsigned short* __restrict__ q,
                                                   unsigned short* __restrict__ k)
{
    int wid = threadIdx.x >> 6, lane = threadIdx.x & 63;
    int id = blockIdx.x * 4 + wid; // t*NH + h
    unsigned short* p = blockIdx.y ? k : q;
    int t = id >> 4, h = id & 15;
    int s = t & (SS - 1);
    size_t off = (size_t)t * DM + h * HD + lane;
    float val = bfb2f(p[off]);
    float ss = wave_sum(val * val);
    float rs = rsqrtf(ss / (float)HD + 1e-6f);
    float nv = val * rs;
    float other = __shfl_xor(nv, 32, 64);
    int j = lane & 31;
    float invf = exp2f(-(float)j * 0.41524101186092025f);
    float fr = (float)s * invf;
    float sn, cs;
    sincosf(fr, &sn, &cs);
    float outv = (lane < 32) ? (nv * cs + other * sn) : (nv * cs - other * sn);
    p[off] = f2bfb(outv);
}

// MFMA flash attention. 256 threads / 4 waves; block = 64 queries of one (b,h).
__global__ __launch_bounds__(256) void attn_mfma_kernel(
    const unsigned short* __restrict__ q, const unsigned short* __restrict__ k,
    const unsigned short* __restrict__ v, unsigned short* __restrict__ y,
    const int* __restrict__ levels)
{
    __shared__ unsigned short Qs[64][APITCH];
    __shared__ unsigned short Ks[64][APITCH];
    __shared__ unsigned short Vt[64][APITCH];
    __shared__ unsigned short Ps[64][APITCH];
    __shared__ int lvlS[64];

    int bh = blockIdx.x;
    int b = bh >> 4, h = bh & 15;
    int q0 = blockIdx.y * 64;
    size_t base = (size_t)b * SS * DM + h * HD;
    int tid = threadIdx.x;
    int lane = tid & 63, w = tid >> 6;
    int srow = tid >> 2, sc = tid & 3;

    {
        const unsigned short* src = q + base + (size_t)(q0 + srow) * DM;
        *reinterpret_cast<uint4*>(&Qs[srow][sc * 8]) = *reinterpret_cast<const uint4*>(src + sc * 8);
        *reinterpret_cast<uint4*>(&Qs[srow][(sc + 4) * 8]) = *reinterpret_cast<const uint4*>(src + (sc + 4) * 8);
    }
    __syncthreads();

    int fr = lane & 15, fc = (lane >> 4) * 8;
    int rj = (lane >> 4) * 4;

    bf16x8 qa[2];
    qa[0] = *reinterpret_cast<const bf16x8*>(&Qs[w * 16 + fr][fc]);
    qa[1] = *reinterpret_cast<const bf16x8*>(&Qs[w * 16 + fr][32 + fc]);

    float mreg[4], lreg[4];
    f32x4 yacc[4];
#pragma unroll
    for (int j = 0; j < 4; ++j) { mreg[j] = -1e30f; lreg[j] = 0.0f; yacc[j] = 0.0f; }

    int ntile = blockIdx.y + 1;
    for (int kt = 0; kt < ntile; ++kt) {
        int k0 = kt * 64;
        __syncthreads();
        {
            size_t goff = base + (size_t)(k0 + srow) * DM;
            uint4 kv0 = *reinterpret_cast<const uint4*>(k + goff + sc * 8);
            uint4 kv1 = *reinterpret_cast<const uint4*>(k + goff + (sc + 4) * 8);
            *reinterpret_cast<uint4*>(&Ks[srow][sc * 8]) = kv0;
            *reinterpret_cast<uint4*>(&Ks[srow][(sc + 4) * 8]) = kv1;
            uint4 vv0 = *reinterpret_cast<const uint4*>(v + goff + sc * 8);
            uint4 vv1 = *reinterpret_cast<const uint4*>(v + goff + (sc + 4) * 8);
            const unsigned short* e0 = reinterpret_cast<const unsigned short*>(&vv0);
            const unsigned short* e1 = reinterpret_cast<const unsigned short*>(&vv1);
#pragma unroll
            for (int i = 0; i < 8; ++i) Vt[sc * 8 + i][srow] = e0[i];
#pragma unroll
            for (int i = 0; i < 8; ++i) Vt[(sc + 4) * 8 + i][srow] = e1[i];
            if (tid < 64) lvlS[tid] = levels[b * SS + k0 + tid];
        }
        __syncthreads();

        f32x4 sacc[4];
#pragma unroll
        for (int n = 0; n < 4; ++n) {
            bf16x8 kb0 = *reinterpret_cast<const bf16x8*>(&Ks[n * 16 + fr][fc]);
            bf16x8 kb1 = *reinterpret_cast<const bf16x8*>(&Ks[n * 16 + fr][32 + fc]);
            f32x4 a = {0.0f, 0.0f, 0.0f, 0.0f};
            a = __builtin_amdgcn_mfma_f32_16x16x32_bf16(qa[0], kb0, a, 0, 0, 0);
            a = __builtin_amdgcn_mfma_f32_16x16x32_bf16(qa[1], kb1, a, 0, 0, 0);
            sacc[n] = a;
        }

        float sm[4][4];
        float cm[4] = {-1e30f, -1e30f, -1e30f, -1e30f};
#pragma unroll
        for (int n = 0; n < 4; ++n) {
            int kg = k0 + n * 16 + fr;
            int L = lvlS[n * 16 + fr];
#pragma unroll
            for (int j = 0; j < 4; ++j) {
                int qg = q0 + w * 16 + rj + j;
                bool valid = (kg <= qg) && (L > 0 || (qg - kg) <= 256);
                float s = valid ? sacc[n][j] * 0.125f : -1e30f;
                sm[n][j] = s;
                cm[j] = fmaxf(cm[j], s);
            }
        }
#pragma unroll
        for (int j = 0; j < 4; ++j) {
            cm[j] = fmaxf(cm[j], __shfl_xor(cm[j], 1, 64));
            cm[j] = fmaxf(cm[j], __shfl_xor(cm[j], 2, 64));
            cm[j] = fmaxf(cm[j], __shfl_xor(cm[j], 4, 64));
            cm[j] = fmaxf(cm[j], __shfl_xor(cm[j], 8, 64));
        }
        float sj[4], ps[4];
#pragma unroll
        for (int j = 0; j < 4; ++j) {
            float nm = fmaxf(mreg[j], cm[j]);
            sj[j] = __expf(mreg[j] - nm);
            mreg[j] = nm;
            ps[j] = 0.0f;
        }
#pragma unroll
        for (int n = 0; n < 4; ++n) {
#pragma unroll
            for (int j = 0; j < 4; ++j) {
                float p = (sm[n][j] > -1e29f) ? __expf(sm[n][j] - mreg[j]) : 0.0f;
                Ps[w * 16 + rj + j][n * 16 + fr] = f2bfb(p);
                ps[j] += p;
            }
        }
#pragma unroll
        for (int j = 0; j < 4; ++j) {
            float t = ps[j];
            t += __shfl_xor(t, 1, 64); t += __shfl_xor(t, 2, 64);
            t += __shfl_xor(t, 4, 64); t += __shfl_xor(t, 8, 64);
            lreg[j] = lreg[j] * sj[j] + t;
        }
#pragma unroll
        for (int n = 0; n < 4; ++n)
#pragma unroll
            for (int j = 0; j < 4; ++j) yacc[n][j] *= sj[j];

        bf16x8 pa0 = *reinterpret_cast<const bf16x8*>(&Ps[w * 16 + fr][fc]);
        bf16x8 pa1 = *reinterpret_cast<const bf16x8*>(&Ps[w * 16 + fr][32 + fc]);
#pragma unroll
        for (int n = 0; n < 4; ++n) {
            bf16x8 vb0 = *reinterpret_cast<const bf16x8*>(&Vt[n * 16 + fr][fc]);
            bf16x8 vb1 = *reinterpret_cast<const bf16x8*>(&Vt[n * 16 + fr][32 + fc]);
            yacc[n] = __builtin_amdgcn_mfma_f32_16x16x32_bf16(pa0, vb0, yacc[n], 0, 0, 0);
            yacc[n] = __builtin_amdgcn_mfma_f32_16x16x32_bf16(pa1, vb1, yacc[n], 0, 0, 0);
        }
    }

    float inv[4];
#pragma unroll
    for (int j = 0; j < 4; ++j) inv[j] = 1.0f / lreg[j];
#pragma unroll
    for (int n = 0; n < 4; ++n) {
#pragma unroll
        for (int j = 0; j < 4; ++j) {
            int qg = q0 + w * 16 + rj + j;
            y[base + (size_t)qg * DM + n * 16 + fr] = f2bfb(yacc[n][j] * inv[j]);
        }
    }
}

// per-token: softcap + logsumexp + NLL
__global__ __launch_bounds__(256) void loss_kernel(
    const unsigned short* __restrict__ logits, const int* __restrict__ target,
    float* __restrict__ out)
{
    int t = blockIdx.x;
    const unsigned short* row = logits + (size_t)t * VP;
    int tg = target[t];
    float m = -1e30f, l = 0.0f, ztg = 0.0f;
    for (int i = threadIdx.x; i < VV; i += 256) {
        float z = bfb2f(row[i]);
        z = 30.0f * tanhf(z * (1.0f / 30.0f));
        if (i == tg) ztg = z;
        if (z > m) {
            l = l * __expf(m - z) + 1.0f;
            m = z;
        } else {
            l += __expf(z - m);
        }
    }
    __shared__ float ms[256], ls[256];
    __shared__ float zs;
    ms[threadIdx.x] = m;
    ls[threadIdx.x] = l;
    if (threadIdx.x == (tg & 255)) zs = ztg;
    for (int s2 = 128; s2 > 0; s2 >>= 1) {
        __syncthreads();
        if (threadIdx.x < s2) {
            float m2 = ms[threadIdx.x + s2], l2 = ls[threadIdx.x + s2];
            float m1 = ms[threadIdx.x], l1 = ls[threadIdx.x];
            float mm = fmaxf(m1, m2);
            ls[threadIdx.x] = l1 * __expf(m1 - mm) + l2 * __expf(m2 - mm);
            ms[threadIdx.x] = mm;
        }
    }
    __syncthreads();
    if (threadIdx.x == 0) {
        float lse = ms[0] + logf(ls[0]);
        float loss = lse - zs;
        bool masked = (tg == 16384) || (tg == 18433) || (tg == 18690);
        out[t] = masked ? 0.0f : loss;
    }
}

extern "C" void kernel_launch(void* const* d_in, const int* in_sizes, int n_in,
                              void* d_out, int out_size, void* d_ws, size_t ws_size,
                              hipStream_t stream)
{
    const int* idx = (const int*)d_in[0];
    const int* target = (const int*)d_in[1];
    const float* wte = (const float*)d_in[2];
    const float* lambdas = (const float*)d_in[3];
    const float* lamb = (const float*)d_in[4];
    const float* wq = (const float*)d_in[5];
    const float* wk = (const float*)d_in[6];
    const float* wv = (const float*)d_in[7];
    const float* wo = (const float*)d_in[8];
    const float* w1 = (const float*)d_in[9];
    const float* w2 = (const float*)d_in[10];
    const float* lm_head = (const float*)d_in[11];
    float* out = (float*)d_out;

    char* ws = (char*)d_ws;
    const size_t MB = (size_t)1 << 20;
    float* x            = (float*)(ws);
    unsigned short* x0  = (unsigned short*)(ws + 16 * MB);
    unsigned short* nrm = (unsigned short*)(ws + 24 * MB);
    unsigned short* qb  = (unsigned short*)(ws + 32 * MB);
    unsigned short* kb  = (unsigned short*)(ws + 40 * MB);
    unsigned short* vb  = (unsigned short*)(ws + 48 * MB);
    unsigned short* v1b = (unsigned short*)(ws + 56 * MB);
    unsigned short* yb  = (unsigned short*)(ws + 64 * MB);
    unsigned short* hid = (unsigned short*)(ws + 72 * MB);
    int* levels         = (int*)(ws + 104 * MB);
    unsigned short* logits = (unsigned short*)(ws + 105 * MB);
    // converted bf16 weights
    unsigned short* wqb = (unsigned short*)(ws + 260 * MB);
    unsigned short* wkb = (unsigned short*)(ws + 268 * MB);
    unsigned short* wvb = (unsigned short*)(ws + 276 * MB);
    unsigned short* wob = (unsigned short*)(ws + 284 * MB);
    unsigned short* w1b = (unsigned short*)(ws + 292 * MB);
    unsigned short* w2b = (unsigned short*)(ws + 324 * MB);
    unsigned short* lmb = (unsigned short*)(ws + 356 * MB);
    bool cvt = ws_size >= 394 * MB;

    if (cvt) {
        int n44 = NL * DM * DM;
        int nff = NL * FFD * DM;
        cvtw_kernel<<<n44 / 1024, 256, 0, stream>>>(wq, wqb, n44);
        cvtw_kernel<<<n44 / 1024, 256, 0, stream>>>(wk, wkb, n44);
        cvtw_kernel<<<n44 / 1024, 256, 0, stream>>>(wv, wvb, n44);
        cvtw_kernel<<<n44 / 1024, 256, 0, stream>>>(wo, wob, n44);
        cvtw_kernel<<<nff / 1024, 256, 0, stream>>>(w1, w1b, nff);
        cvtw_kernel<<<nff / 1024, 256, 0, stream>>>(w2, w2b, nff);
        cvtpad_kernel<<<(VP * DM) / 1024, 256, 0, stream>>>(lm_head, lmb, VV * DM, VP * DM);
    }

    embed_kernel<<<TT, 256, 0, stream>>>(idx, wte, x, x0, levels);

    for (int i = 0; i < NL; ++i) {
        mixnorm_kernel<<<TT, 256, 0, stream>>>(x, x0, lambdas + 2 * i, nrm);
        if (cvt) {
            gemm_bb<0><<<256, 256, 0, stream>>>(nrm, wqb + (size_t)i * DM * DM, qb, nullptr, 8, DM, DM);
            gemm_bb<0><<<256, 256, 0, stream>>>(nrm, wkb + (size_t)i * DM * DM, kb, nullptr, 8, DM, DM);
            gemm_bb<0><<<256, 256, 0, stream>>>(nrm, wvb + (size_t)i * DM * DM, vb, nullptr, 8, DM, DM);
        } else {
            dim3 g8(8, 32);
            gemm_bt<0><<<g8, 256, 0, stream>>>(nrm, wq + (size_t)i * DM * DM, qb, nullptr, TT, DM, DM, DM);
            gemm_bt<0><<<g8, 256, 0, stream>>>(nrm, wk + (size_t)i * DM * DM, kb, nullptr, TT, DM, DM, DM);
            gemm_bt<0><<<g8, 256, 0, stream>>>(nrm, wv + (size_t)i * DM * DM, vb, nullptr, TT, DM, DM, DM);
        }
        if (i == 0)
            vcopy_kernel<<<TT * DM / 1024, 256, 0, stream>>>(vb, v1b);
        else
            vmix_kernel<<<TT * DM / 1024, 256, 0, stream>>>(vb, v1b, lamb + i);
        rope_kernel<<<dim3(TT * NH / 4, 2), 256, 0, stream>>>(qb, kb);
        attn_mfma_kernel<<<dim3(BBATCH * NH, SS / 64), 256, 0, stream>>>(qb, kb, vb, yb, levels);
        if (cvt) {
            gemm_bb<2><<<256, 256, 0, stream>>>(yb, wob + (size_t)i * DM * DM, nullptr, x, 8, DM, DM);
            norm_kernel<<<TT, 256, 0, stream>>>(x, nrm);
            gemm_bb<1><<<1024, 256, 0, stream>>>(nrm, w1b + (size_t)i * FFD * DM, hid, nullptr, 32, DM, FFD);
            gemm_bb<2><<<256, 256, 0, stream>>>(hid, w2b + (size_t)i * DM * FFD, nullptr, x, 8, FFD, DM);
        } else {
            dim3 g8(8, 32);
            gemm_bt<2><<<g8, 256, 0, stream>>>(yb, wo + (size_t)i * DM * DM, nullptr, x, TT, DM, DM, DM);
            norm_kernel<<<TT, 256, 0, stream>>>(x, nrm);
            gemm_bt<1><<<dim3(32, 32), 256, 0, stream>>>(nrm, w1 + (size_t)i * FFD * DM, hid, nullptr, TT, FFD, DM, FFD);
            gemm_bt<2><<<g8, 256, 0, stream>>>(hid, w2 + (size_t)i * DM * FFD, nullptr, x, TT, DM, FFD, DM);
        }
    }

    norm_kernel<<<TT, 256, 0, stream>>>(x, nrm);
    if (cvt)
        gemm_bb<0><<<147 * 32, 256, 0, stream>>>(nrm, lmb, logits, nullptr, 147, DM, VP);
    else
        gemm_bt<0><<<dim3(VP / 128, 32), 256, 0, stream>>>(nrm, lm_head, logits, nullptr, TT, VV, DM, VP);
    loss_kernel<<<TT, 256, 0, stream>>>(logits, target, out);
}

// Round 4
// 2037.895 us; speedup vs baseline: 2.4518x; 1.3393x over previous
//
#include <hip/hip_runtime.h>
#include <hip/hip_bf16.h>

#define TT 4096
#define SS 2048
#define BBATCH 2
#define DM 1024
#define NH 16
#define HD 64
#define FFD 4096
#define NL 4
#define VV 18691
#define VP 18816
#define APITCH 72
#define LCHUNK 6272

typedef __bf16 bf16x8 __attribute__((ext_vector_type(8)));
typedef float f32x4 __attribute__((ext_vector_type(4)));
typedef const __attribute__((address_space(1))) void* gas_t;
typedef __attribute__((address_space(3))) void* las_t;

__device__ __forceinline__ float bfb2f(unsigned short u) {
    union { unsigned int i; float f; } x;
    x.i = ((unsigned int)u) << 16;
    return x.f;
}
__device__ __forceinline__ unsigned short f2bfb(float f) {
    union { float f; unsigned int i; } x;
    x.f = f;
    unsigned int r = 0x7fffu + ((x.i >> 16) & 1u);
    x.i += r;
    return (unsigned short)(x.i >> 16);
}
__device__ __forceinline__ unsigned int pack2(float lo, float hi) {
    return (unsigned int)f2bfb(lo) | ((unsigned int)f2bfb(hi) << 16);
}

__device__ __forceinline__ float wave_sum(float v) {
#pragma unroll
    for (int o = 32; o; o >>= 1) v += __shfl_xor(v, o, 64);
    return v;
}

__device__ __forceinline__ float block_sum256(float v) {
    __shared__ float sb[4];
    v = wave_sum(v);
    int wid = threadIdx.x >> 6;
    if ((threadIdx.x & 63) == 0) sb[wid] = v;
    __syncthreads();
    float t = sb[0] + sb[1] + sb[2] + sb[3];
    __syncthreads();
    return t;
}

// ---- weight fp32 -> bf16 conversion ----
__global__ __launch_bounds__(256) void cvtw_kernel(const float* __restrict__ src,
                                                   unsigned short* __restrict__ dst, int n)
{
    int i = (blockIdx.x * 256 + threadIdx.x) * 4;
    if (i >= n) return;
    float4 f = *reinterpret_cast<const float4*>(src + i);
    ushort4 u;
    u.x = f2bfb(f.x); u.y = f2bfb(f.y); u.z = f2bfb(f.z); u.w = f2bfb(f.w);
    *reinterpret_cast<ushort4*>(dst + i) = u;
}

__global__ __launch_bounds__(256) void cvtpad_kernel(const float* __restrict__ src,
                                                     unsigned short* __restrict__ dst,
                                                     int nreal, int ntot)
{
    int i = (blockIdx.x * 256 + threadIdx.x) * 4;
    if (i >= ntot) return;
    ushort4 u = {0, 0, 0, 0};
    if (i < nreal) {
        float4 f = *reinterpret_cast<const float4*>(src + i);
        u.x = f2bfb(f.x); u.y = f2bfb(f.y); u.z = f2bfb(f.z); u.w = f2bfb(f.w);
    }
    *reinterpret_cast<ushort4*>(dst + i) = u;
}

// x = rms_norm(wte[idx]); x0 = bf16(x); levels[t]
__global__ __launch_bounds__(256) void embed_kernel(
    const int* __restrict__ idx, const float* __restrict__ wte,
    float* __restrict__ x, unsigned short* __restrict__ x0, int* __restrict__ levels)
{
    int t = blockIdx.x;
    int id = idx[t];
    const float* row = wte + (size_t)id * DM;
    float4 v = *reinterpret_cast<const float4*>(row + threadIdx.x * 4);
    float ss = v.x * v.x + v.y * v.y + v.z * v.z + v.w * v.w;
    float tot = block_sum256(ss);
    float rs = rsqrtf(tot / (float)DM + 1e-6f);
    float4 o;
    o.x = v.x * rs; o.y = v.y * rs; o.z = v.z * rs; o.w = v.w * rs;
    size_t off = (size_t)t * DM + threadIdx.x * 4;
    *reinterpret_cast<float4*>(x + off) = o;
    ushort4 ub;
    ub.x = f2bfb(o.x); ub.y = f2bfb(o.y); ub.z = f2bfb(o.z); ub.w = f2bfb(o.w);
    *reinterpret_cast<ushort4*>(x0 + off) = ub;
    if (threadIdx.x == 0) levels[t] = (id >= 16385) + (id >= 18434);
}

// xr = l0*x + l1*x0 (written back to x); out = bf16(rms_norm(xr))
__global__ __launch_bounds__(256) void mixnorm_kernel(
    float* __restrict__ x, const unsigned short* __restrict__ x0,
    const float* __restrict__ lam2, unsigned short* __restrict__ out)
{
    int t = blockIdx.x;
    size_t off = (size_t)t * DM + threadIdx.x * 4;
    float4 xv = *reinterpret_cast<const float4*>(x + off);
    float l0 = lam2[0], l1 = lam2[1];
    ushort4 u = *reinterpret_cast<const ushort4*>(x0 + off);
    float4 r;
    r.x = l0 * xv.x + l1 * bfb2f(u.x);
    r.y = l0 * xv.y + l1 * bfb2f(u.y);
    r.z = l0 * xv.z + l1 * bfb2f(u.z);
    r.w = l0 * xv.w + l1 * bfb2f(u.w);
    float ss = r.x * r.x + r.y * r.y + r.z * r.z + r.w * r.w;
    float tot = block_sum256(ss);
    float rs = rsqrtf(tot / (float)DM + 1e-6f);
    *reinterpret_cast<float4*>(x + off) = r;
    ushort4 ob;
    ob.x = f2bfb(r.x * rs); ob.y = f2bfb(r.y * rs);
    ob.z = f2bfb(r.z * rs); ob.w = f2bfb(r.w * rs);
    *reinterpret_cast<ushort4*>(out + off) = ob;
}

// out = bf16(rms_norm(x)), x unmodified
__global__ __launch_bounds__(256) void norm_kernel(
    const float* __restrict__ x, unsigned short* __restrict__ out)
{
    int t = blockIdx.x;
    size_t off = (size_t)t * DM + threadIdx.x * 4;
    float4 r = *reinterpret_cast<const float4*>(x + off);
    float ss = r.x * r.x + r.y * r.y + r.z * r.z + r.w * r.w;
    float tot = block_sum256(ss);
    float rs = rsqrtf(tot / (float)DM + 1e-6f);
    ushort4 ob;
    ob.x = f2bfb(r.x * rs); ob.y = f2bfb(r.y * rs);
    ob.z = f2bfb(r.z * rs); ob.w = f2bfb(r.w * rs);
    *reinterpret_cast<ushort4*>(out + off) = ob;
}

// ---------- bf16-weight GEMM, m97 structure ----------
// C[4096][N] = A(bf16 [4096][K]) @ W^T, W bf16 [N][K]; N mult of 128, K mult of 64.
// 128x128 tile, BK=64, global_load_lds w=16, T2 swizzle (inverse-swizzled source + swizzled read).
template <int EPI>
__global__ __launch_bounds__(256) void gemm_bb(
    const unsigned short* __restrict__ A, const unsigned short* __restrict__ Bw,
    unsigned short* __restrict__ Cb, float* __restrict__ Cf,
    int NX, int K, int ldC)
{
    __shared__ unsigned short As[128 * 64];
    __shared__ unsigned short Bs[128 * 64];

    int nwg = gridDim.x;
    int orig = blockIdx.x;
    int qq = nwg >> 3, rr = nwg & 7;
    int xcd = orig & 7, rem = orig >> 3;
    int wg = (xcd < rr ? xcd * (qq + 1) : rr * (qq + 1) + (xcd - rr) * qq) + rem;
    int bx = wg % NX, by = wg / NX;
    int m0 = by * 128, n0 = bx * 128;

    int tid = threadIdx.x, lane = tid & 63, w = tid >> 6;
    int wr = w >> 1, wc = w & 1;
    int rsub = lane >> 3, sl = lane & 7;
    int ssrc = sl ^ rsub;           // inverse-swizzled source slot
    int fr = lane & 15, fh = lane >> 4;

    size_t arow[4], brow[4];
#pragma unroll
    for (int i = 0; i < 4; ++i) {
        int c = 4 * w + i;
        arow[i] = (size_t)(m0 + 8 * c + rsub) * K + ssrc * 8;
        brow[i] = (size_t)(n0 + 8 * c + rsub) * K + ssrc * 8;
    }

    f32x4 acc[4][4];
#pragma unroll
    for (int m = 0; m < 4; ++m)
#pragma unroll
        for (int n = 0; n < 4; ++n) acc[m][n] = 0.0f;

    int NT = K >> 6;
    for (int kt = 0; kt < NT; ++kt) {
        int kb = kt * 64;
#pragma unroll
        for (int i = 0; i < 4; ++i) {
            __builtin_amdgcn_global_load_lds((gas_t)(const void*)(A + arow[i] + kb),
                                             (las_t)(void*)(&As[(4 * w + i) * 512]), 16, 0, 0);
            __builtin_amdgcn_global_load_lds((gas_t)(const void*)(Bw + brow[i] + kb),
                                             (las_t)(void*)(&Bs[(4 * w + i) * 512]), 16, 0, 0);
        }
        __syncthreads();
#pragma unroll
        for (int kk = 0; kk < 2; ++kk) {
            int slot = kk * 4 + fh;
            bf16x8 af[4], bfv[4];
#pragma unroll
            for (int m = 0; m < 4; ++m) {
                int row = wr * 64 + m * 16 + fr;
                af[m] = *reinterpret_cast<const bf16x8*>(&As[row * 64 + ((slot ^ (row & 7)) << 3)]);
            }
#pragma unroll
            for (int n = 0; n < 4; ++n) {
                int row = wc * 64 + n * 16 + fr;
                bfv[n] = *reinterpret_cast<const bf16x8*>(&Bs[row * 64 + ((slot ^ (row & 7)) << 3)]);
            }
#pragma unroll
            for (int m = 0; m < 4; ++m)
#pragma unroll
                for (int n = 0; n < 4; ++n)
                    acc[m][n] = __builtin_amdgcn_mfma_f32_16x16x32_bf16(af[m], bfv[n], acc[m][n], 0, 0, 0);
        }
        __syncthreads();
    }

    int rb = m0 + wr * 64 + fh * 4;
    int cb = n0 + wc * 64 + fr;
#pragma unroll
    for (int n = 0; n < 4; ++n) {
        int gc = cb + n * 16;
#pragma unroll
        for (int m = 0; m < 4; ++m) {
#pragma unroll
            for (int j = 0; j < 4; ++j) {
                int gr = rb + m * 16 + j;
                float val = acc[m][n][j];
                if constexpr (EPI == 0) {
                    Cb[(size_t)gr * ldC + gc] = f2bfb(val);
                } else if constexpr (EPI == 1) {
                    float rl = fmaxf(val, 0.0f);
                    Cb[(size_t)gr * ldC + gc] = f2bfb(rl * rl);
                } else {
                    size_t o = (size_t)gr * ldC + gc;
                    Cf[o] = Cf[o] + val;
                }
            }
        }
    }
}

// ---------- fp32-weight GEMM (fallback only) ----------
template <int EPI>
__global__ __launch_bounds__(256) void gemm_bt(
    const unsigned short* __restrict__ A, const float* __restrict__ Bw,
    unsigned short* __restrict__ Cb, float* __restrict__ Cf,
    int M, int N, int K, int ldC)
{
    __shared__ unsigned short As[128][40];
    __shared__ unsigned short Bs[128][40];
    int tid = threadIdx.x;
    int lane = tid & 63, wave = tid >> 6;
    int wr = wave >> 1, wc = wave & 1;
    int m0 = blockIdx.y * 128, n0 = blockIdx.x * 128;
    int sr = tid >> 2, scc = (tid & 3) * 8;

    const unsigned short* pA0 = A + (size_t)(m0 + sr) * K + scc;
    const unsigned short* pA1 = A + (size_t)(m0 + sr + 64) * K + scc;
    const float* pB0 = Bw + (size_t)(n0 + sr) * K + scc;
    const float* pB1 = Bw + (size_t)(n0 + sr + 64) * K + scc;
    bool ok0 = (n0 + sr) < N, ok1 = (n0 + sr + 64) < N;

    f32x4 acc[4][4];
#pragma unroll
    for (int m = 0; m < 4; ++m)
#pragma unroll
        for (int n = 0; n < 4; ++n) acc[m][n] = 0.0f;

    int fr = lane & 15, fchunk = (lane >> 4) * 8;

    for (int kt = 0; kt < K; kt += 32) {
        int4 av0 = *reinterpret_cast<const int4*>(pA0 + kt);
        int4 av1 = *reinterpret_cast<const int4*>(pA1 + kt);
        float4 b00 = {0, 0, 0, 0}, b01 = {0, 0, 0, 0}, b10 = {0, 0, 0, 0}, b11 = {0, 0, 0, 0};
        if (ok0) { b00 = *reinterpret_cast<const float4*>(pB0 + kt); b01 = *reinterpret_cast<const float4*>(pB0 + kt + 4); }
        if (ok1) { b10 = *reinterpret_cast<const float4*>(pB1 + kt); b11 = *reinterpret_cast<const float4*>(pB1 + kt + 4); }
        __syncthreads();
        *reinterpret_cast<int4*>(&As[sr][scc]) = av0;
        *reinterpret_cast<int4*>(&As[sr + 64][scc]) = av1;
        uint4 bp0, bp1;
        bp0.x = pack2(b00.x, b00.y); bp0.y = pack2(b00.z, b00.w);
        bp0.z = pack2(b01.x, b01.y); bp0.w = pack2(b01.z, b01.w);
        bp1.x = pack2(b10.x, b10.y); bp1.y = pack2(b10.z, b10.w);
        bp1.z = pack2(b11.x, b11.y); bp1.w = pack2(b11.z, b11.w);
        *reinterpret_cast<uint4*>(&Bs[sr][scc]) = bp0;
        *reinterpret_cast<uint4*>(&Bs[sr + 64][scc]) = bp1;
        __syncthreads();
        bf16x8 af[4], bfv[4];
#pragma unroll
        for (int m = 0; m < 4; ++m)
            af[m] = *reinterpret_cast<const bf16x8*>(&As[wr * 64 + m * 16 + fr][fchunk]);
#pragma unroll
        for (int n = 0; n < 4; ++n)
            bfv[n] = *reinterpret_cast<const bf16x8*>(&Bs[wc * 64 + n * 16 + fr][fchunk]);
#pragma unroll
        for (int m = 0; m < 4; ++m)
#pragma unroll
            for (int n = 0; n < 4; ++n)
                acc[m][n] = __builtin_amdgcn_mfma_f32_16x16x32_bf16(af[m], bfv[n], acc[m][n], 0, 0, 0);
    }

    int rb = m0 + wr * 64 + (lane >> 4) * 4;
    int cb = n0 + wc * 64 + (lane & 15);
#pragma unroll
    for (int n = 0; n < 4; ++n) {
        int gc = cb + n * 16;
        if (gc >= N) continue;
#pragma unroll
        for (int m = 0; m < 4; ++m) {
#pragma unroll
            for (int j = 0; j < 4; ++j) {
                int gr = rb + m * 16 + j;
                float val = acc[m][n][j];
                if constexpr (EPI == 0) {
                    Cb[(size_t)gr * ldC + gc] = f2bfb(val);
                } else if constexpr (EPI == 1) {
                    float rl = fmaxf(val, 0.0f);
                    Cb[(size_t)gr * ldC + gc] = f2bfb(rl * rl);
                } else {
                    size_t o = (size_t)gr * ldC + gc;
                    Cf[o] = Cf[o] + val;
                }
            }
        }
    }
}

__global__ void vcopy_kernel(const unsigned short* __restrict__ v, unsigned short* __restrict__ v1)
{
    int i = blockIdx.x * 256 + threadIdx.x;
    reinterpret_cast<ushort4*>(v1)[i] = reinterpret_cast<const ushort4*>(v)[i];
}

__global__ void vmix_kernel(unsigned short* __restrict__ v, const unsigned short* __restrict__ v1,
                            const float* __restrict__ lamb)
{
    int i = blockIdx.x * 256 + threadIdx.x;
    float la = *lamb;
    ushort4 a = reinterpret_cast<const ushort4*>(v)[i];
    ushort4 b = reinterpret_cast<const ushort4*>(v1)[i];
    ushort4 o;
    o.x = f2bfb((1.0f - la) * bfb2f(a.x) + la * bfb2f(b.x));
    o.y = f2bfb((1.0f - la) * bfb2f(a.y) + la * bfb2f(b.y));
    o.z = f2bfb((1.0f - la) * bfb2f(a.z) + la * bfb2f(b.z));
    o.w = f2bfb((1.0f - la) * bfb2f(a.w) + la * bfb2f(b.w));
    reinterpret_cast<ushort4*>(v)[i] = o;
}

// per-(t,h) head rms_norm + rotary; applied in-place to q (blockIdx.y==0) or k (==1)
__global__ __launch_bounds__(256) void rope_kernel(unsigned short* __restrict__ q,
                                                   unsigned short* __restrict__ k)
{
    int wid = threadIdx.x >> 6, lane = threadIdx.x & 63;
    int id = blockIdx.x * 4 + wid; // t*NH + h
    unsigned short* p = blockIdx.y ? k : q;
    int t = id >> 4, h = id & 15;
    int s = t & (SS - 1);
    size_t off = (size_t)t * DM + h * HD + lane;
    float val = bfb2f(p[off]);
    float ss = wave_sum(val * val);
    float rs = rsqrtf(ss / (float)HD + 1e-6f);
    float nv = val * rs;
    float other = __shfl_xor(nv, 32, 64);
    int j = lane & 31;
    float invf = exp2f(-(float)j * 0.41524101186092025f);
    float fr = (float)s * invf;
    float sn, cs;
    sincosf(fr, &sn, &cs);
    float outv = (lane < 32) ? (nv * cs + other * sn) : (nv * cs - other * sn);
    p[off] = f2bfb(outv);
}

// MFMA flash attention. 256 threads / 4 waves; block = 64 queries of one (b,h).
__global__ __launch_bounds__(256) void attn_mfma_kernel(
    const unsigned short* __restrict__ q, const unsigned short* __restrict__ k,
    const unsigned short* __restrict__ v, unsigned short* __restrict__ y,
    const int* __restrict__ levels)
{
    __shared__ unsigned short Qs[64][APITCH];
    __shared__ unsigned short Ks[64][APITCH];
    __shared__ unsigned short Vt[64][APITCH];
    __shared__ unsigned short Ps[64][APITCH];
    __shared__ int lvlS[64];

    int bh = blockIdx.x;
    int b = bh >> 4, h = bh & 15;
    int q0 = blockIdx.y * 64;
    size_t base = (size_t)b * SS * DM + h * HD;
    int tid = threadIdx.x;
    int lane = tid & 63, w = tid >> 6;
    int srow = tid >> 2, sc = tid & 3;

    {
        const unsigned short* src = q + base + (size_t)(q0 + srow) * DM;
        *reinterpret_cast<uint4*>(&Qs[srow][sc * 8]) = *reinterpret_cast<const uint4*>(src + sc * 8);
        *reinterpret_cast<uint4*>(&Qs[srow][(sc + 4) * 8]) = *reinterpret_cast<const uint4*>(src + (sc + 4) * 8);
    }
    __syncthreads();

    int fr = lane & 15, fc = (lane >> 4) * 8;
    int rj = (lane >> 4) * 4;

    bf16x8 qa[2];
    qa[0] = *reinterpret_cast<const bf16x8*>(&Qs[w * 16 + fr][fc]);
    qa[1] = *reinterpret_cast<const bf16x8*>(&Qs[w * 16 + fr][32 + fc]);

    float mreg[4], lreg[4];
    f32x4 yacc[4];
#pragma unroll
    for (int j = 0; j < 4; ++j) { mreg[j] = -1e30f; lreg[j] = 0.0f; yacc[j] = 0.0f; }

    int ntile = blockIdx.y + 1;
    for (int kt = 0; kt < ntile; ++kt) {
        int k0 = kt * 64;
        __syncthreads();
        {
            size_t goff = base + (size_t)(k0 + srow) * DM;
            uint4 kv0 = *reinterpret_cast<const uint4*>(k + goff + sc * 8);
            uint4 kv1 = *reinterpret_cast<const uint4*>(k + goff + (sc + 4) * 8);
            *reinterpret_cast<uint4*>(&Ks[srow][sc * 8]) = kv0;
            *reinterpret_cast<uint4*>(&Ks[srow][(sc + 4) * 8]) = kv1;
            uint4 vv0 = *reinterpret_cast<const uint4*>(v + goff + sc * 8);
            uint4 vv1 = *reinterpret_cast<const uint4*>(v + goff + (sc + 4) * 8);
            const unsigned short* e0 = reinterpret_cast<const unsigned short*>(&vv0);
            const unsigned short* e1 = reinterpret_cast<const unsigned short*>(&vv1);
#pragma unroll
            for (int i = 0; i < 8; ++i) Vt[sc * 8 + i][srow] = e0[i];
#pragma unroll
            for (int i = 0; i < 8; ++i) Vt[(sc + 4) * 8 + i][srow] = e1[i];
            if (tid < 64) lvlS[tid] = levels[b * SS + k0 + tid];
        }
        __syncthreads();

        f32x4 sacc[4];
#pragma unroll
        for (int n = 0; n < 4; ++n) {
            bf16x8 kb0 = *reinterpret_cast<const bf16x8*>(&Ks[n * 16 + fr][fc]);
            bf16x8 kb1 = *reinterpret_cast<const bf16x8*>(&Ks[n * 16 + fr][32 + fc]);
            f32x4 a = {0.0f, 0.0f, 0.0f, 0.0f};
            a = __builtin_amdgcn_mfma_f32_16x16x32_bf16(qa[0], kb0, a, 0, 0, 0);
            a = __builtin_amdgcn_mfma_f32_16x16x32_bf16(qa[1], kb1, a, 0, 0, 0);
            sacc[n] = a;
        }

        float sm[4][4];
        float cm[4] = {-1e30f, -1e30f, -1e30f, -1e30f};
#pragma unroll
        for (int n = 0; n < 4; ++n) {
            int kg = k0 + n * 16 + fr;
            int L = lvlS[n * 16 + fr];
#pragma unroll
            for (int j = 0; j < 4; ++j) {
                int qg = q0 + w * 16 + rj + j;
                bool valid = (kg <= qg) && (L > 0 || (qg - kg) <= 256);
                float s = valid ? sacc[n][j] * 0.125f : -1e30f;
                sm[n][j] = s;
                cm[j] = fmaxf(cm[j], s);
            }
        }
#pragma unroll
        for (int j = 0; j < 4; ++j) {
            cm[j] = fmaxf(cm[j], __shfl_xor(cm[j], 1, 64));
            cm[j] = fmaxf(cm[j], __shfl_xor(cm[j], 2, 64));
            cm[j] = fmaxf(cm[j], __shfl_xor(cm[j], 4, 64));
            cm[j] = fmaxf(cm[j], __shfl_xor(cm[j], 8, 64));
        }
        float sj[4], ps[4];
#pragma unroll
        for (int j = 0; j < 4; ++j) {
            float nm = fmaxf(mreg[j], cm[j]);
            sj[j] = __expf(mreg[j] - nm);
            mreg[j] = nm;
            ps[j] = 0.0f;
        }
#pragma unroll
        for (int n = 0; n < 4; ++n) {
#pragma unroll
            for (int j = 0; j < 4; ++j) {
                float p = (sm[n][j] > -1e29f) ? __expf(sm[n][j] - mreg[j]) : 0.0f;
                Ps[w * 16 + rj + j][n * 16 + fr] = f2bfb(p);
                ps[j] += p;
            }
        }
#pragma unroll
        for (int j = 0; j < 4; ++j) {
            float t = ps[j];
            t += __shfl_xor(t, 1, 64); t += __shfl_xor(t, 2, 64);
            t += __shfl_xor(t, 4, 64); t += __shfl_xor(t, 8, 64);
            lreg[j] = lreg[j] * sj[j] + t;
        }
#pragma unroll
        for (int n = 0; n < 4; ++n)
#pragma unroll
            for (int j = 0; j < 4; ++j) yacc[n][j] *= sj[j];

        bf16x8 pa0 = *reinterpret_cast<const bf16x8*>(&Ps[w * 16 + fr][fc]);
        bf16x8 pa1 = *reinterpret_cast<const bf16x8*>(&Ps[w * 16 + fr][32 + fc]);
#pragma unroll
        for (int n = 0; n < 4; ++n) {
            bf16x8 vb0 = *reinterpret_cast<const bf16x8*>(&Vt[n * 16 + fr][fc]);
            bf16x8 vb1 = *reinterpret_cast<const bf16x8*>(&Vt[n * 16 + fr][32 + fc]);
            yacc[n] = __builtin_amdgcn_mfma_f32_16x16x32_bf16(pa0, vb0, yacc[n], 0, 0, 0);
            yacc[n] = __builtin_amdgcn_mfma_f32_16x16x32_bf16(pa1, vb1, yacc[n], 0, 0, 0);
        }
    }

    float inv[4];
#pragma unroll
    for (int j = 0; j < 4; ++j) inv[j] = 1.0f / lreg[j];
#pragma unroll
    for (int n = 0; n < 4; ++n) {
#pragma unroll
        for (int j = 0; j < 4; ++j) {
            int qg = q0 + w * 16 + rj + j;
            y[base + (size_t)qg * DM + n * 16 + fr] = f2bfb(yacc[n][j] * inv[j]);
        }
    }
}

// chunked loss: softcap + partial LSE over [c0, c0+cn), merged into per-token state.
__global__ __launch_bounds__(256) void loss_part_kernel(
    const unsigned short* __restrict__ logits, const int* __restrict__ target,
    float* __restrict__ mbuf, float* __restrict__ lbuf, float* __restrict__ zbuf,
    float* __restrict__ out, int c0, int cn, int last)
{
    int t = blockIdx.x;
    const unsigned short* row = logits + (size_t)t * cn;
    int tg = target[t];
    int tl = tg - c0;
    int lim = min(cn, VV - c0);
    float m = -1e30f, l = 0.0f, ztg = 0.0f;
    for (int i = threadIdx.x; i < lim; i += 256) {
        float z = bfb2f(row[i]);
        z = 30.0f * tanhf(z * (1.0f / 30.0f));
        if (i == tl) ztg = z;
        if (z > m) {
            l = l * __expf(m - z) + 1.0f;
            m = z;
        } else {
            l += __expf(z - m);
        }
    }
    __shared__ float ms[256], ls[256];
    __shared__ float zs;
    if (threadIdx.x == 0) zs = 0.0f;
    ms[threadIdx.x] = m;
    ls[threadIdx.x] = l;
    __syncthreads();
    if (tl >= 0 && tl < lim && threadIdx.x == (tl & 255)) zs = ztg;
    for (int s2 = 128; s2 > 0; s2 >>= 1) {
        __syncthreads();
        if (threadIdx.x < s2) {
            float m2 = ms[threadIdx.x + s2], l2 = ls[threadIdx.x + s2];
            float m1 = ms[threadIdx.x], l1 = ls[threadIdx.x];
            float mm = fmaxf(m1, m2);
            ls[threadIdx.x] = l1 * __expf(m1 - mm) + l2 * __expf(m2 - mm);
            ms[threadIdx.x] = mm;
        }
    }
    __syncthreads();
    if (threadIdx.x == 0) {
        float cmv = ms[0], clv = ls[0], czv = zs;
        float nm, nl, nz;
        if (c0 == 0) {
            nm = cmv; nl = clv; nz = czv;
        } else {
            float pm = mbuf[t], pl = lbuf[t];
            nm = fmaxf(pm, cmv);
            nl = pl * __expf(pm - nm) + clv * __expf(cmv - nm);
            nz = zbuf[t] + czv;
        }
        if (last) {
            float lse = nm + logf(nl);
            bool masked = (tg == 16384) || (tg == 18433) || (tg == 18690);
            out[t] = masked ? 0.0f : (lse - nz);
        } else {
            mbuf[t] = nm; lbuf[t] = nl; zbuf[t] = nz;
        }
    }
}

// full-vocab loss (fallback path)
__global__ __launch_bounds__(256) void loss_kernel(
    const unsigned short* __restrict__ logits, const int* __restrict__ target,
    float* __restrict__ out)
{
    int t = blockIdx.x;
    const unsigned short* row = logits + (size_t)t * VP;
    int tg = target[t];
    float m = -1e30f, l = 0.0f, ztg = 0.0f;
    for (int i = threadIdx.x; i < VV; i += 256) {
        float z = bfb2f(row[i]);
        z = 30.0f * tanhf(z * (1.0f / 30.0f));
        if (i == tg) ztg = z;
        if (z > m) {
            l = l * __expf(m - z) + 1.0f;
            m = z;
        } else {
            l += __expf(z - m);
        }
    }
    __shared__ float ms[256], ls[256];
    __shared__ float zs;
    ms[threadIdx.x] = m;
    ls[threadIdx.x] = l;
    if (threadIdx.x == (tg & 255)) zs = ztg;
    for (int s2 = 128; s2 > 0; s2 >>= 1) {
        __syncthreads();
        if (threadIdx.x < s2) {
            float m2 = ms[threadIdx.x + s2], l2 = ls[threadIdx.x + s2];
            float m1 = ms[threadIdx.x], l1 = ls[threadIdx.x];
            float mm = fmaxf(m1, m2);
            ls[threadIdx.x] = l1 * __expf(m1 - mm) + l2 * __expf(m2 - mm);
            ms[threadIdx.x] = mm;
        }
    }
    __syncthreads();
    if (threadIdx.x == 0) {
        float lse = ms[0] + logf(ls[0]);
        float loss = lse - zs;
        bool masked = (tg == 16384) || (tg == 18433) || (tg == 18690);
        out[t] = masked ? 0.0f : loss;
    }
}

extern "C" void kernel_launch(void* const* d_in, const int* in_sizes, int n_in,
                              void* d_out, int out_size, void* d_ws, size_t ws_size,
                              hipStream_t stream)
{
    const int* idx = (const int*)d_in[0];
    const int* target = (const int*)d_in[1];
    const float* wte = (const float*)d_in[2];
    const float* lambdas = (const float*)d_in[3];
    const float* lamb = (const float*)d_in[4];
    const float* wq = (const float*)d_in[5];
    const float* wk = (const float*)d_in[6];
    const float* wv = (const float*)d_in[7];
    const float* wo = (const float*)d_in[8];
    const float* w1 = (const float*)d_in[9];
    const float* w2 = (const float*)d_in[10];
    const float* lm_head = (const float*)d_in[11];
    float* out = (float*)d_out;

    char* ws = (char*)d_ws;
    const size_t MB = (size_t)1 << 20;
    float* x            = (float*)(ws);
    unsigned short* x0  = (unsigned short*)(ws + 16 * MB);
    unsigned short* nrm = (unsigned short*)(ws + 24 * MB);
    unsigned short* qb  = (unsigned short*)(ws + 32 * MB);
    unsigned short* kb  = (unsigned short*)(ws + 40 * MB);
    unsigned short* vb  = (unsigned short*)(ws + 48 * MB);
    unsigned short* v1b = (unsigned short*)(ws + 56 * MB);
    unsigned short* yb  = (unsigned short*)(ws + 64 * MB);
    unsigned short* hid = (unsigned short*)(ws + 72 * MB);
    int* levels         = (int*)(ws + 104 * MB);
    float* mbuf         = (float*)(ws + 104 * MB + 256 * 1024);
    float* lbuf         = mbuf + TT;
    float* zbuf         = lbuf + TT;
    // bf16 weights at [105, 237.75) MB; logits chunk reuses [32, 81.25) MB at lm time
    unsigned short* wqb = (unsigned short*)(ws + 105 * MB);
    unsigned short* wkb = (unsigned short*)(ws + 113 * MB);
    unsigned short* wvb = (unsigned short*)(ws + 121 * MB);
    unsigned short* wob = (unsigned short*)(ws + 129 * MB);
    unsigned short* w1b = (unsigned short*)(ws + 137 * MB);
    unsigned short* w2b = (unsigned short*)(ws + 169 * MB);
    unsigned short* lmb = (unsigned short*)(ws + 201 * MB);
    unsigned short* lchunk = qb; // 49 MB spanning qb..hid, dead at lm time
    unsigned short* logits_full = (unsigned short*)(ws + 105 * MB); // fallback only
    bool cvt = ws_size >= 238 * MB;

    if (cvt) {
        int n44 = NL * DM * DM;
        int nff = NL * FFD * DM;
        cvtw_kernel<<<n44 / 1024, 256, 0, stream>>>(wq, wqb, n44);
        cvtw_kernel<<<n44 / 1024, 256, 0, stream>>>(wk, wkb, n44);
        cvtw_kernel<<<n44 / 1024, 256, 0, stream>>>(wv, wvb, n44);
        cvtw_kernel<<<n44 / 1024, 256, 0, stream>>>(wo, wob, n44);
        cvtw_kernel<<<nff / 1024, 256, 0, stream>>>(w1, w1b, nff);
        cvtw_kernel<<<nff / 1024, 256, 0, stream>>>(w2, w2b, nff);
        cvtpad_kernel<<<(VP * DM) / 1024, 256, 0, stream>>>(lm_head, lmb, VV * DM, VP * DM);
    }

    embed_kernel<<<TT, 256, 0, stream>>>(idx, wte, x, x0, levels);

    for (int i = 0; i < NL; ++i) {
        mixnorm_kernel<<<TT, 256, 0, stream>>>(x, x0, lambdas + 2 * i, nrm);
        if (cvt) {
            gemm_bb<0><<<256, 256, 0, stream>>>(nrm, wqb + (size_t)i * DM * DM, qb, nullptr, 8, DM, DM);
            gemm_bb<0><<<256, 256, 0, stream>>>(nrm, wkb + (size_t)i * DM * DM, kb, nullptr, 8, DM, DM);
            gemm_bb<0><<<256, 256, 0, stream>>>(nrm, wvb + (size_t)i * DM * DM, vb, nullptr, 8, DM, DM);
        } else {
            dim3 g8(8, 32);
            gemm_bt<0><<<g8, 256, 0, stream>>>(nrm, wq + (size_t)i * DM * DM, qb, nullptr, TT, DM, DM, DM);
            gemm_bt<0><<<g8, 256, 0, stream>>>(nrm, wk + (size_t)i * DM * DM, kb, nullptr, TT, DM, DM, DM);
            gemm_bt<0><<<g8, 256, 0, stream>>>(nrm, wv + (size_t)i * DM * DM, vb, nullptr, TT, DM, DM, DM);
        }
        if (i == 0)
            vcopy_kernel<<<TT * DM / 1024, 256, 0, stream>>>(vb, v1b);
        else
            vmix_kernel<<<TT * DM / 1024, 256, 0, stream>>>(vb, v1b, lamb + i);
        rope_kernel<<<dim3(TT * NH / 4, 2), 256, 0, stream>>>(qb, kb);
        attn_mfma_kernel<<<dim3(BBATCH * NH, SS / 64), 256, 0, stream>>>(qb, kb, vb, yb, levels);
        if (cvt) {
            gemm_bb<2><<<256, 256, 0, stream>>>(yb, wob + (size_t)i * DM * DM, nullptr, x, 8, DM, DM);
            norm_kernel<<<TT, 256, 0, stream>>>(x, nrm);
            gemm_bb<1><<<1024, 256, 0, stream>>>(nrm, w1b + (size_t)i * FFD * DM, hid, nullptr, 32, DM, FFD);
            gemm_bb<2><<<256, 256, 0, stream>>>(hid, w2b + (size_t)i * DM * FFD, nullptr, x, 8, FFD, DM);
        } else {
            dim3 g8(8, 32);
            gemm_bt<2><<<g8, 256, 0, stream>>>(yb, wo + (size_t)i * DM * DM, nullptr, x, TT, DM, DM, DM);
            norm_kernel<<<TT, 256, 0, stream>>>(x, nrm);
            gemm_bt<1><<<dim3(32, 32), 256, 0, stream>>>(nrm, w1 + (size_t)i * FFD * DM, hid, nullptr, TT, FFD, DM, FFD);
            gemm_bt<2><<<g8, 256, 0, stream>>>(hid, w2 + (size_t)i * DM * FFD, nullptr, x, TT, DM, FFD, DM);
        }
    }

    norm_kernel<<<TT, 256, 0, stream>>>(x, nrm);
    if (cvt) {
        for (int c = 0; c < 3; ++c) {
            gemm_bb<0><<<(LCHUNK / 128) * 32, 256, 0, stream>>>(
                nrm, lmb + (size_t)c * LCHUNK * DM, lchunk, nullptr, LCHUNK / 128, DM, LCHUNK);
            loss_part_kernel<<<TT, 256, 0, stream>>>(lchunk, target, mbuf, lbuf, zbuf,
                                                     out, c * LCHUNK, LCHUNK, c == 2);
        }
    } else {
        gemm_bt<0><<<dim3(VP / 128, 32), 256, 0, stream>>>(nrm, lm_head, logits_full, nullptr, TT, VV, DM, VP);
        loss_kernel<<<TT, 256, 0, stream>>>(logits_full, target, out);
    }
}

// Round 5
// 1640.626 us; speedup vs baseline: 3.0456x; 1.2421x over previous
//
#include <hip/hip_runtime.h>
#include <hip/hip_bf16.h>

#define TT 4096
#define SS 2048
#define BBATCH 2
#define DM 1024
#define NH 16
#define HD 64
#define FFD 4096
#define NL 4
#define VV 18691
#define VP 18816
#define APITCH 72
#define LCHUNK 6272
#define SENT 0x3FFFFFFF

typedef __bf16 bf16x8 __attribute__((ext_vector_type(8)));
typedef float f32x4 __attribute__((ext_vector_type(4)));
typedef const __attribute__((address_space(1))) void* gas_t;
typedef __attribute__((address_space(3))) void* las_t;

__device__ __forceinline__ float bfb2f(unsigned short u) {
    union { unsigned int i; float f; } x;
    x.i = ((unsigned int)u) << 16;
    return x.f;
}
__device__ __forceinline__ unsigned short f2bfb(float f) {
    union { float f; unsigned int i; } x;
    x.f = f;
    unsigned int r = 0x7fffu + ((x.i >> 16) & 1u);
    x.i += r;
    return (unsigned short)(x.i >> 16);
}
__device__ __forceinline__ unsigned int pack2(float lo, float hi) {
    return (unsigned int)f2bfb(lo) | ((unsigned int)f2bfb(hi) << 16);
}

__device__ __forceinline__ float wave_sum(float v) {
#pragma unroll
    for (int o = 32; o; o >>= 1) v += __shfl_xor(v, o, 64);
    return v;
}

__device__ __forceinline__ float block_sum256(float v) {
    __shared__ float sb[4];
    v = wave_sum(v);
    int wid = threadIdx.x >> 6;
    if ((threadIdx.x & 63) == 0) sb[wid] = v;
    __syncthreads();
    float t = sb[0] + sb[1] + sb[2] + sb[3];
    __syncthreads();
    return t;
}

// ---- weight fp32 -> bf16 conversion ----
__global__ __launch_bounds__(256) void cvtw_kernel(const float* __restrict__ src,
                                                   unsigned short* __restrict__ dst, int n)
{
    int i = (blockIdx.x * 256 + threadIdx.x) * 4;
    if (i >= n) return;
    float4 f = *reinterpret_cast<const float4*>(src + i);
    ushort4 u;
    u.x = f2bfb(f.x); u.y = f2bfb(f.y); u.z = f2bfb(f.z); u.w = f2bfb(f.w);
    *reinterpret_cast<ushort4*>(dst + i) = u;
}

__global__ __launch_bounds__(256) void cvtpad_kernel(const float* __restrict__ src,
                                                     unsigned short* __restrict__ dst,
                                                     int nreal, int ntot)
{
    int i = (blockIdx.x * 256 + threadIdx.x) * 4;
    if (i >= ntot) return;
    ushort4 u = {0, 0, 0, 0};
    if (i < nreal) {
        float4 f = *reinterpret_cast<const float4*>(src + i);
        u.x = f2bfb(f.x); u.y = f2bfb(f.y); u.z = f2bfb(f.z); u.w = f2bfb(f.w);
    }
    *reinterpret_cast<ushort4*>(dst + i) = u;
}

// x = rms_norm(wte[idx]); x0 = bf16(x); levels[t]
__global__ __launch_bounds__(256) void embed_kernel(
    const int* __restrict__ idx, const float* __restrict__ wte,
    float* __restrict__ x, unsigned short* __restrict__ x0, int* __restrict__ levels)
{
    int t = blockIdx.x;
    int id = idx[t];
    const float* row = wte + (size_t)id * DM;
    float4 v = *reinterpret_cast<const float4*>(row + threadIdx.x * 4);
    float ss = v.x * v.x + v.y * v.y + v.z * v.z + v.w * v.w;
    float tot = block_sum256(ss);
    float rs = rsqrtf(tot / (float)DM + 1e-6f);
    float4 o;
    o.x = v.x * rs; o.y = v.y * rs; o.z = v.z * rs; o.w = v.w * rs;
    size_t off = (size_t)t * DM + threadIdx.x * 4;
    *reinterpret_cast<float4*>(x + off) = o;
    ushort4 ub;
    ub.x = f2bfb(o.x); ub.y = f2bfb(o.y); ub.z = f2bfb(o.z); ub.w = f2bfb(o.w);
    *reinterpret_cast<ushort4*>(x0 + off) = ub;
    if (threadIdx.x == 0) levels[t] = (id >= 16385) + (id >= 18434);
}

// per-batch ascending list of positions with level>0
__global__ __launch_bounds__(256) void pack_kernel(
    const int* __restrict__ levels, int* __restrict__ gpos, int* __restrict__ nbuf)
{
    int b = blockIdx.x;
    const int* lv = levels + b * SS;
    int* gp = gpos + b * SS;
    __shared__ int wsum[4];
    __shared__ int base;
    if (threadIdx.x == 0) base = 0;
    __syncthreads();
    int lane = threadIdx.x & 63, w = threadIdx.x >> 6;
    for (int c = 0; c < SS; c += 256) {
        int s = c + threadIdx.x;
        int flag = (lv[s] > 0) ? 1 : 0;
        unsigned long long mask = __ballot(flag);
        int pre = __popcll(mask & ((1ull << lane) - 1ull));
        int wtot = __popcll(mask);
        if (lane == 0) wsum[w] = wtot;
        __syncthreads();
        int woff = 0;
#pragma unroll
        for (int i = 0; i < 4; ++i) if (i < w) woff += wsum[i];
        int tot = wsum[0] + wsum[1] + wsum[2] + wsum[3];
        int mybase = base;
        if (flag) gp[mybase + woff + pre] = s;
        __syncthreads();
        if (threadIdx.x == 0) base += tot;
        __syncthreads();
    }
    int nb = base;
    int nbp = (nb + 63) & ~63;
    for (int i = nb + threadIdx.x; i < SS; i += 256) gp[i] = SENT;
    if (threadIdx.x == 0) { nbuf[b] = nb; nbuf[BBATCH + b] = nbp; }
}

// gather roped K and mixed V rows of level>0 positions into packed buffers
__global__ __launch_bounds__(64) void gather_kernel(
    const unsigned short* __restrict__ kb, const unsigned short* __restrict__ vb,
    const int* __restrict__ gpos, const int* __restrict__ nbuf,
    unsigned short* __restrict__ kp, unsigned short* __restrict__ vp)
{
    int b = blockIdx.x >> 11;
    int j = blockIdx.x & (SS - 1);
    if (j >= nbuf[BBATCH + b]) return;
    int pos = gpos[b * SS + j];
    int lane = threadIdx.x;
    size_t dst = ((size_t)b * SS + j) * DM + lane * 16;
    if (pos < SS) {
        size_t src = ((size_t)b * SS + pos) * DM + lane * 16;
        *reinterpret_cast<uint4*>(kp + dst) = *reinterpret_cast<const uint4*>(kb + src);
        *reinterpret_cast<uint4*>(kp + dst + 8) = *reinterpret_cast<const uint4*>(kb + src + 8);
        *reinterpret_cast<uint4*>(vp + dst) = *reinterpret_cast<const uint4*>(vb + src);
        *reinterpret_cast<uint4*>(vp + dst + 8) = *reinterpret_cast<const uint4*>(vb + src + 8);
    } else {
        uint4 z = {0, 0, 0, 0};
        *reinterpret_cast<uint4*>(kp + dst) = z;
        *reinterpret_cast<uint4*>(kp + dst + 8) = z;
        *reinterpret_cast<uint4*>(vp + dst) = z;
        *reinterpret_cast<uint4*>(vp + dst + 8) = z;
    }
}

// xr = l0*x + l1*x0 (written back to x); out = bf16(rms_norm(xr))
__global__ __launch_bounds__(256) void mixnorm_kernel(
    float* __restrict__ x, const unsigned short* __restrict__ x0,
    const float* __restrict__ lam2, unsigned short* __restrict__ out)
{
    int t = blockIdx.x;
    size_t off = (size_t)t * DM + threadIdx.x * 4;
    float4 xv = *reinterpret_cast<const float4*>(x + off);
    float l0 = lam2[0], l1 = lam2[1];
    ushort4 u = *reinterpret_cast<const ushort4*>(x0 + off);
    float4 r;
    r.x = l0 * xv.x + l1 * bfb2f(u.x);
    r.y = l0 * xv.y + l1 * bfb2f(u.y);
    r.z = l0 * xv.z + l1 * bfb2f(u.z);
    r.w = l0 * xv.w + l1 * bfb2f(u.w);
    float ss = r.x * r.x + r.y * r.y + r.z * r.z + r.w * r.w;
    float tot = block_sum256(ss);
    float rs = rsqrtf(tot / (float)DM + 1e-6f);
    *reinterpret_cast<float4*>(x + off) = r;
    ushort4 ob;
    ob.x = f2bfb(r.x * rs); ob.y = f2bfb(r.y * rs);
    ob.z = f2bfb(r.z * rs); ob.w = f2bfb(r.w * rs);
    *reinterpret_cast<ushort4*>(out + off) = ob;
}

// out = bf16(rms_norm(x)), x unmodified
__global__ __launch_bounds__(256) void norm_kernel(
    const float* __restrict__ x, unsigned short* __restrict__ out)
{
    int t = blockIdx.x;
    size_t off = (size_t)t * DM + threadIdx.x * 4;
    float4 r = *reinterpret_cast<const float4*>(x + off);
    float ss = r.x * r.x + r.y * r.y + r.z * r.z + r.w * r.w;
    float tot = block_sum256(ss);
    float rs = rsqrtf(tot / (float)DM + 1e-6f);
    ushort4 ob;
    ob.x = f2bfb(r.x * rs); ob.y = f2bfb(r.y * rs);
    ob.z = f2bfb(r.z * rs); ob.w = f2bfb(r.w * rs);
    *reinterpret_cast<ushort4*>(out + off) = ob;
}

// ---------- bf16-weight GEMM, m97 structure ----------
// C[4096][N] = A(bf16 [4096][K]) @ W^T, W bf16 [N][K]; N mult of 128, K mult of 64.
// EPI 0: C bf16. EPI 1: relu(acc)^2 bf16. EPI 2: Cf fp32 += acc. EPI 3: fused QKV split.
template <int EPI>
__global__ __launch_bounds__(256) void gemm_bb(
    const unsigned short* __restrict__ A, const unsigned short* __restrict__ Bw,
    unsigned short* __restrict__ Cb, float* __restrict__ Cf,
    unsigned short* __restrict__ Kb, unsigned short* __restrict__ Vb,
    int NX, int K, int ldC)
{
    __shared__ unsigned short As[128 * 64];
    __shared__ unsigned short Bs[128 * 64];

    int nwg = gridDim.x;
    int orig = blockIdx.x;
    int qq = nwg >> 3, rr = nwg & 7;
    int xcd = orig & 7, rem = orig >> 3;
    int wg = (xcd < rr ? xcd * (qq + 1) : rr * (qq + 1) + (xcd - rr) * qq) + rem;
    int bx = wg % NX, by = wg / NX;
    int m0 = by * 128, n0 = bx * 128;

    int tid = threadIdx.x, lane = tid & 63, w = tid >> 6;
    int wr = w >> 1, wc = w & 1;
    int rsub = lane >> 3, sl = lane & 7;
    int ssrc = sl ^ rsub;           // inverse-swizzled source slot
    int fr = lane & 15, fh = lane >> 4;

    size_t arow[4], brow[4];
#pragma unroll
    for (int i = 0; i < 4; ++i) {
        int c = 4 * w + i;
        arow[i] = (size_t)(m0 + 8 * c + rsub) * K + ssrc * 8;
        brow[i] = (size_t)(n0 + 8 * c + rsub) * K + ssrc * 8;
    }

    f32x4 acc[4][4];
#pragma unroll
    for (int m = 0; m < 4; ++m)
#pragma unroll
        for (int n = 0; n < 4; ++n) acc[m][n] = 0.0f;

    int NT = K >> 6;
    for (int kt = 0; kt < NT; ++kt) {
        int kb = kt * 64;
#pragma unroll
        for (int i = 0; i < 4; ++i) {
            __builtin_amdgcn_global_load_lds((gas_t)(const void*)(A + arow[i] + kb),
                                             (las_t)(void*)(&As[(4 * w + i) * 512]), 16, 0, 0);
            __builtin_amdgcn_global_load_lds((gas_t)(const void*)(Bw + brow[i] + kb),
                                             (las_t)(void*)(&Bs[(4 * w + i) * 512]), 16, 0, 0);
        }
        __syncthreads();
#pragma unroll
        for (int kk = 0; kk < 2; ++kk) {
            int slot = kk * 4 + fh;
            bf16x8 af[4], bfv[4];
#pragma unroll
            for (int m = 0; m < 4; ++m) {
                int row = wr * 64 + m * 16 + fr;
                af[m] = *reinterpret_cast<const bf16x8*>(&As[row * 64 + ((slot ^ (row & 7)) << 3)]);
            }
#pragma unroll
            for (int n = 0; n < 4; ++n) {
                int row = wc * 64 + n * 16 + fr;
                bfv[n] = *reinterpret_cast<const bf16x8*>(&Bs[row * 64 + ((slot ^ (row & 7)) << 3)]);
            }
#pragma unroll
            for (int m = 0; m < 4; ++m)
#pragma unroll
                for (int n = 0; n < 4; ++n)
                    acc[m][n] = __builtin_amdgcn_mfma_f32_16x16x32_bf16(af[m], bfv[n], acc[m][n], 0, 0, 0);
        }
        __syncthreads();
    }

    int rb = m0 + wr * 64 + fh * 4;
    int cb = n0 + wc * 64 + fr;
    unsigned short* outp = Cb;
    if constexpr (EPI == 3) {
        int mat = n0 >> 10;
        outp = (mat == 0) ? Cb : ((mat == 1) ? Kb : Vb);
    }
#pragma unroll
    for (int n = 0; n < 4; ++n) {
        int gc = cb + n * 16;
#pragma unroll
        for (int m = 0; m < 4; ++m) {
#pragma unroll
            for (int j = 0; j < 4; ++j) {
                int gr = rb + m * 16 + j;
                float val = acc[m][n][j];
                if constexpr (EPI == 0) {
                    Cb[(size_t)gr * ldC + gc] = f2bfb(val);
                } else if constexpr (EPI == 1) {
                    float rl = fmaxf(val, 0.0f);
                    Cb[(size_t)gr * ldC + gc] = f2bfb(rl * rl);
                } else if constexpr (EPI == 2) {
                    size_t o = (size_t)gr * ldC + gc;
                    Cf[o] = Cf[o] + val;
                } else {
                    outp[(size_t)gr * DM + (gc & 1023)] = f2bfb(val);
                }
            }
        }
    }
}

__global__ void vcopy_kernel(const unsigned short* __restrict__ v, unsigned short* __restrict__ v1)
{
    int i = blockIdx.x * 256 + threadIdx.x;
    reinterpret_cast<ushort4*>(v1)[i] = reinterpret_cast<const ushort4*>(v)[i];
}

__global__ void vmix_kernel(unsigned short* __restrict__ v, const unsigned short* __restrict__ v1,
                            const float* __restrict__ lamb)
{
    int i = blockIdx.x * 256 + threadIdx.x;
    float la = *lamb;
    ushort4 a = reinterpret_cast<const ushort4*>(v)[i];
    ushort4 b = reinterpret_cast<const ushort4*>(v1)[i];
    ushort4 o;
    o.x = f2bfb((1.0f - la) * bfb2f(a.x) + la * bfb2f(b.x));
    o.y = f2bfb((1.0f - la) * bfb2f(a.y) + la * bfb2f(b.y));
    o.z = f2bfb((1.0f - la) * bfb2f(a.z) + la * bfb2f(b.z));
    o.w = f2bfb((1.0f - la) * bfb2f(a.w) + la * bfb2f(b.w));
    reinterpret_cast<ushort4*>(v)[i] = o;
}

// per-(t,h) head rms_norm + rotary; applied in-place to q (blockIdx.y==0) or k (==1)
__global__ __launch_bounds__(256) void rope_kernel(unsigned short* __restrict__ q,
                                                   unsigned short* __restrict__ k)
{
    int wid = threadIdx.x >> 6, lane = threadIdx.x & 63;
    int id = blockIdx.x * 4 + wid; // t*NH + h
    unsigned short* p = blockIdx.y ? k : q;
    int t = id >> 4, h = id & 15;
    int s = t & (SS - 1);
    size_t off = (size_t)t * DM + h * HD + lane;
    float val = bfb2f(p[off]);
    float ss = wave_sum(val * val);
    float rs = rsqrtf(ss / (float)HD + 1e-6f);
    float nv = val * rs;
    float other = __shfl_xor(nv, 32, 64);
    int j = lane & 31;
    float invf = exp2f(-(float)j * 0.41524101186092025f);
    float fr = (float)s * invf;
    float sn, cs;
    sincosf(fr, &sn, &cs);
    float outv = (lane < 32) ? (nv * cs + other * sn) : (nv * cs - other * sn);
    p[off] = f2bfb(outv);
}

// MFMA flash attention, mask-sparse: local sliding-window pass + packed level>0 pass.
// 256 threads / 4 waves; block = 64 queries of one (b,h).
__global__ __launch_bounds__(256) void attn_mfma_kernel(
    const unsigned short* __restrict__ q, const unsigned short* __restrict__ k,
    const unsigned short* __restrict__ v,
    const unsigned short* __restrict__ kp, const unsigned short* __restrict__ vp,
    const int* __restrict__ gpos, const int* __restrict__ nbuf,
    unsigned short* __restrict__ y)
{
    __shared__ unsigned short Qs[64][APITCH];
    __shared__ unsigned short Ks[64][APITCH];
    __shared__ unsigned short Vt[64][APITCH];
    __shared__ unsigned short Ps[64][APITCH];
    __shared__ int posS[64];

    int bh = blockIdx.x;
    int b = bh >> 4, h = bh & 15;
    int q0 = blockIdx.y * 64;
    size_t base = (size_t)b * SS * DM + h * HD;
    size_t pbase = (size_t)b * SS * DM + h * HD; // same indexing for packed buffers
    int tid = threadIdx.x;
    int lane = tid & 63, w = tid >> 6;
    int srow = tid >> 2, sc = tid & 3;

    {
        const unsigned short* src = q + base + (size_t)(q0 + srow) * DM;
        *reinterpret_cast<uint4*>(&Qs[srow][sc * 8]) = *reinterpret_cast<const uint4*>(src + sc * 8);
        *reinterpret_cast<uint4*>(&Qs[srow][(sc + 4) * 8]) = *reinterpret_cast<const uint4*>(src + (sc + 4) * 8);
    }
    __syncthreads();

    int fr = lane & 15, fc = (lane >> 4) * 8;
    int rj = (lane >> 4) * 4;

    bf16x8 qa[2];
    qa[0] = *reinterpret_cast<const bf16x8*>(&Qs[w * 16 + fr][fc]);
    qa[1] = *reinterpret_cast<const bf16x8*>(&Qs[w * 16 + fr][32 + fc]);

    float mreg[4], lreg[4];
    f32x4 yacc[4];
#pragma unroll
    for (int j = 0; j < 4; ++j) { mreg[j] = -1e30f; lreg[j] = 0.0f; yacc[j] = 0.0f; }

    int nbp = nbuf[BBATCH + b];

    // ---------------- pass 0: local window (causal && delta<=256) ----------------
    int t0 = (q0 >= 256) ? ((q0 - 256) >> 6) : 0;
    int t1 = q0 >> 6;
    // ---------------- pass 1: packed level>0 keys (pos < qg-256) ----------------
    for (int pass = 0; pass < 2; ++pass) {
        int kt_begin = (pass == 0) ? t0 : 0;
        int kt_end = (pass == 0) ? (t1 + 1) : (nbp >> 6);
        for (int kt = kt_begin; kt < kt_end; ++kt) {
            int k0 = kt * 64;
            if (pass == 1) {
                if (gpos[b * SS + k0] > q0 - 194) break; // ascending: nothing valid beyond
            }
            __syncthreads();
            {
                const unsigned short* ksrc = (pass == 0) ? (k + base) : (kp + pbase);
                const unsigned short* vsrc = (pass == 0) ? (v + base) : (vp + pbase);
                size_t goff = (size_t)(k0 + srow) * DM;
                uint4 kv0 = *reinterpret_cast<const uint4*>(ksrc + goff + sc * 8);
                uint4 kv1 = *reinterpret_cast<const uint4*>(ksrc + goff + (sc + 4) * 8);
                *reinterpret_cast<uint4*>(&Ks[srow][sc * 8]) = kv0;
                *reinterpret_cast<uint4*>(&Ks[srow][(sc + 4) * 8]) = kv1;
                uint4 vv0 = *reinterpret_cast<const uint4*>(vsrc + goff + sc * 8);
                uint4 vv1 = *reinterpret_cast<const uint4*>(vsrc + goff + (sc + 4) * 8);
                const unsigned short* e0 = reinterpret_cast<const unsigned short*>(&vv0);
                const unsigned short* e1 = reinterpret_cast<const unsigned short*>(&vv1);
#pragma unroll
                for (int i = 0; i < 8; ++i) Vt[sc * 8 + i][srow] = e0[i];
#pragma unroll
                for (int i = 0; i < 8; ++i) Vt[(sc + 4) * 8 + i][srow] = e1[i];
                if (pass == 1 && tid < 64) posS[tid] = gpos[b * SS + k0 + tid];
            }
            __syncthreads();

            f32x4 sacc[4];
#pragma unroll
            for (int n = 0; n < 4; ++n) {
                bf16x8 kb0 = *reinterpret_cast<const bf16x8*>(&Ks[n * 16 + fr][fc]);
                bf16x8 kb1 = *reinterpret_cast<const bf16x8*>(&Ks[n * 16 + fr][32 + fc]);
                f32x4 a = {0.0f, 0.0f, 0.0f, 0.0f};
                a = __builtin_amdgcn_mfma_f32_16x16x32_bf16(qa[0], kb0, a, 0, 0, 0);
                a = __builtin_amdgcn_mfma_f32_16x16x32_bf16(qa[1], kb1, a, 0, 0, 0);
                sacc[n] = a;
            }

            float sm[4][4];
            float cm[4] = {-1e30f, -1e30f, -1e30f, -1e30f};
#pragma unroll
            for (int n = 0; n < 4; ++n) {
                int kg = (pass == 0) ? (k0 + n * 16 + fr) : posS[n * 16 + fr];
#pragma unroll
                for (int j = 0; j < 4; ++j) {
                    int qg = q0 + w * 16 + rj + j;
                    bool valid = (pass == 0) ? ((kg <= qg) && (qg - kg <= 256))
                                             : (kg < qg - 256);
                    float s = valid ? sacc[n][j] * 0.125f : -1e30f;
                    sm[n][j] = s;
                    cm[j] = fmaxf(cm[j], s);
                }
            }
#pragma unroll
            for (int j = 0; j < 4; ++j) {
                cm[j] = fmaxf(cm[j], __shfl_xor(cm[j], 1, 64));
                cm[j] = fmaxf(cm[j], __shfl_xor(cm[j], 2, 64));
                cm[j] = fmaxf(cm[j], __shfl_xor(cm[j], 4, 64));
                cm[j] = fmaxf(cm[j], __shfl_xor(cm[j], 8, 64));
            }
            float sj[4], ps[4];
#pragma unroll
            for (int j = 0; j < 4; ++j) {
                float nm = fmaxf(mreg[j], cm[j]);
                sj[j] = __expf(mreg[j] - nm);
                mreg[j] = nm;
                ps[j] = 0.0f;
            }
#pragma unroll
            for (int n = 0; n < 4; ++n) {
#pragma unroll
                for (int j = 0; j < 4; ++j) {
                    float p = (sm[n][j] > -1e29f) ? __expf(sm[n][j] - mreg[j]) : 0.0f;
                    Ps[w * 16 + rj + j][n * 16 + fr] = f2bfb(p);
                    ps[j] += p;
                }
            }
#pragma unroll
            for (int j = 0; j < 4; ++j) {
                float t = ps[j];
                t += __shfl_xor(t, 1, 64); t += __shfl_xor(t, 2, 64);
                t += __shfl_xor(t, 4, 64); t += __shfl_xor(t, 8, 64);
                lreg[j] = lreg[j] * sj[j] + t;
            }
#pragma unroll
            for (int n = 0; n < 4; ++n)
#pragma unroll
                for (int j = 0; j < 4; ++j) yacc[n][j] *= sj[j];

            bf16x8 pa0 = *reinterpret_cast<const bf16x8*>(&Ps[w * 16 + fr][fc]);
            bf16x8 pa1 = *reinterpret_cast<const bf16x8*>(&Ps[w * 16 + fr][32 + fc]);
#pragma unroll
            for (int n = 0; n < 4; ++n) {
                bf16x8 vb0 = *reinterpret_cast<const bf16x8*>(&Vt[n * 16 + fr][fc]);
                bf16x8 vb1 = *reinterpret_cast<const bf16x8*>(&Vt[n * 16 + fr][32 + fc]);
                yacc[n] = __builtin_amdgcn_mfma_f32_16x16x32_bf16(pa0, vb0, yacc[n], 0, 0, 0);
                yacc[n] = __builtin_amdgcn_mfma_f32_16x16x32_bf16(pa1, vb1, yacc[n], 0, 0, 0);
            }
        }
    }

    float inv[4];
#pragma unroll
    for (int j = 0; j < 4; ++j) inv[j] = 1.0f / lreg[j];
#pragma unroll
    for (int n = 0; n < 4; ++n) {
#pragma unroll
        for (int j = 0; j < 4; ++j) {
            int qg = q0 + w * 16 + rj + j;
            y[base + (size_t)qg * DM + n * 16 + fr] = f2bfb(yacc[n][j] * inv[j]);
        }
    }
}

// chunked loss: softcap + partial LSE over [c0, c0+cn), merged into per-token state.
__global__ __launch_bounds__(256) void loss_part_kernel(
    const unsigned short* __restrict__ logits, const int* __restrict__ target,
    float* __restrict__ mbuf, float* __restrict__ lbuf, float* __restrict__ zbuf,
    float* __restrict__ out, int c0, int cn, int last)
{
    int t = blockIdx.x;
    const unsigned short* row = logits + (size_t)t * cn;
    int tg = target[t];
    int tl = tg - c0;
    int lim = min(cn, VV - c0);
    float m = -1e30f, l = 0.0f, ztg = 0.0f;
    for (int i = threadIdx.x; i < lim; i += 256) {
        float z = bfb2f(row[i]);
        z = 30.0f * tanhf(z * (1.0f / 30.0f));
        if (i == tl) ztg = z;
        if (z > m) {
            l = l * __expf(m - z) + 1.0f;
            m = z;
        } else {
            l += __expf(z - m);
        }
    }
    __shared__ float ms[256], ls[256];
    __shared__ float zs;
    if (threadIdx.x == 0) zs = 0.0f;
    ms[threadIdx.x] = m;
    ls[threadIdx.x] = l;
    __syncthreads();
    if (tl >= 0 && tl < lim && threadIdx.x == (tl & 255)) zs = ztg;
    for (int s2 = 128; s2 > 0; s2 >>= 1) {
        __syncthreads();
        if (threadIdx.x < s2) {
            float m2 = ms[threadIdx.x + s2], l2 = ls[threadIdx.x + s2];
            float m1 = ms[threadIdx.x], l1 = ls[threadIdx.x];
            float mm = fmaxf(m1, m2);
            ls[threadIdx.x] = l1 * __expf(m1 - mm) + l2 * __expf(m2 - mm);
            ms[threadIdx.x] = mm;
        }
    }
    __syncthreads();
    if (threadIdx.x == 0) {
        float cmv = ms[0], clv = ls[0], czv = zs;
        float nm, nl, nz;
        if (c0 == 0) {
            nm = cmv; nl = clv; nz = czv;
        } else {
            float pm = mbuf[t], pl = lbuf[t];
            nm = fmaxf(pm, cmv);
            nl = pl * __expf(pm - nm) + clv * __expf(cmv - nm);
            nz = zbuf[t] + czv;
        }
        if (last) {
            float lse = nm + logf(nl);
            bool masked = (tg == 16384) || (tg == 18433) || (tg == 18690);
            out[t] = masked ? 0.0f : (lse - nz);
        } else {
            mbuf[t] = nm; lbuf[t] = nl; zbuf[t] = nz;
        }
    }
}

extern "C" void kernel_launch(void* const* d_in, const int* in_sizes, int n_in,
                              void* d_out, int out_size, void* d_ws, size_t ws_size,
                              hipStream_t stream)
{
    const int* idx = (const int*)d_in[0];
    const int* target = (const int*)d_in[1];
    const float* wte = (const float*)d_in[2];
    const float* lambdas = (const float*)d_in[3];
    const float* lamb = (const float*)d_in[4];
    const float* wq = (const float*)d_in[5];
    const float* wk = (const float*)d_in[6];
    const float* wv = (const float*)d_in[7];
    const float* wo = (const float*)d_in[8];
    const float* w1 = (const float*)d_in[9];
    const float* w2 = (const float*)d_in[10];
    const float* lm_head = (const float*)d_in[11];
    float* out = (float*)d_out;

    char* ws = (char*)d_ws;
    const size_t MB = (size_t)1 << 20;
    float* x            = (float*)(ws);
    unsigned short* x0  = (unsigned short*)(ws + 16 * MB);
    unsigned short* nrm = (unsigned short*)(ws + 24 * MB);
    unsigned short* qb  = (unsigned short*)(ws + 32 * MB);
    unsigned short* kb  = (unsigned short*)(ws + 40 * MB);
    unsigned short* vb  = (unsigned short*)(ws + 48 * MB);
    unsigned short* v1b = (unsigned short*)(ws + 56 * MB);
    unsigned short* yb  = (unsigned short*)(ws + 64 * MB);
    unsigned short* hid = (unsigned short*)(ws + 72 * MB);   // 32 MB; dead during attention
    unsigned short* kp  = (unsigned short*)(ws + 72 * MB);   // packed K (8 MB), overlaps hid
    unsigned short* vp  = (unsigned short*)(ws + 80 * MB);   // packed V (8 MB), overlaps hid
    int* levels         = (int*)(ws + 104 * MB);
    int* gpos           = (int*)(ws + 104 * MB + 64 * 1024);
    int* nbuf           = (int*)(ws + 104 * MB + 128 * 1024);
    float* mbuf         = (float*)(ws + 104 * MB + 256 * 1024);
    float* lbuf         = mbuf + TT;
    float* zbuf         = lbuf + TT;
    // bf16 weights at [105, 237.75) MB; logits chunk reuses [32, 81.25) MB at lm time
    unsigned short* wqkvb = (unsigned short*)(ws + 105 * MB); // [NL][3][1024][1024]
    unsigned short* wob = (unsigned short*)(ws + 129 * MB);
    unsigned short* w1b = (unsigned short*)(ws + 137 * MB);
    unsigned short* w2b = (unsigned short*)(ws + 169 * MB);
    unsigned short* lmb = (unsigned short*)(ws + 201 * MB);
    unsigned short* lchunk = qb; // 49 MB spanning qb..hid, dead at lm time
    bool cvt = ws_size >= 238 * MB;

    if (cvt) {
        int n1 = DM * DM;
        int nff = NL * FFD * DM;
        for (int i = 0; i < NL; ++i) {
            cvtw_kernel<<<n1 / 1024, 256, 0, stream>>>(wq + (size_t)i * n1, wqkvb + ((size_t)i * 3 + 0) * n1, n1);
            cvtw_kernel<<<n1 / 1024, 256, 0, stream>>>(wk + (size_t)i * n1, wqkvb + ((size_t)i * 3 + 1) * n1, n1);
            cvtw_kernel<<<n1 / 1024, 256, 0, stream>>>(wv + (size_t)i * n1, wqkvb + ((size_t)i * 3 + 2) * n1, n1);
        }
        cvtw_kernel<<<NL * n1 / 1024, 256, 0, stream>>>(wo, wob, NL * n1);
        cvtw_kernel<<<nff / 1024, 256, 0, stream>>>(w1, w1b, nff);
        cvtw_kernel<<<nff / 1024, 256, 0, stream>>>(w2, w2b, nff);
        cvtpad_kernel<<<(VP * DM) / 1024, 256, 0, stream>>>(lm_head, lmb, VV * DM, VP * DM);
    }

    embed_kernel<<<TT, 256, 0, stream>>>(idx, wte, x, x0, levels);
    pack_kernel<<<BBATCH, 256, 0, stream>>>(levels, gpos, nbuf);

    for (int i = 0; i < NL; ++i) {
        mixnorm_kernel<<<TT, 256, 0, stream>>>(x, x0, lambdas + 2 * i, nrm);
        if (cvt) {
            gemm_bb<3><<<768, 256, 0, stream>>>(nrm, wqkvb + (size_t)i * 3 * DM * DM,
                                                qb, nullptr, kb, vb, 24, DM, DM);
        }
        if (i == 0)
            vcopy_kernel<<<TT * DM / 1024, 256, 0, stream>>>(vb, v1b);
        else
            vmix_kernel<<<TT * DM / 1024, 256, 0, stream>>>(vb, v1b, lamb + i);
        rope_kernel<<<dim3(TT * NH / 4, 2), 256, 0, stream>>>(qb, kb);
        gather_kernel<<<BBATCH * SS, 64, 0, stream>>>(kb, vb, gpos, nbuf, kp, vp);
        attn_mfma_kernel<<<dim3(BBATCH * NH, SS / 64), 256, 0, stream>>>(qb, kb, vb, kp, vp, gpos, nbuf, yb);
        if (cvt) {
            gemm_bb<2><<<256, 256, 0, stream>>>(yb, wob + (size_t)i * DM * DM, nullptr, x, nullptr, nullptr, 8, DM, DM);
            norm_kernel<<<TT, 256, 0, stream>>>(x, nrm);
            gemm_bb<1><<<1024, 256, 0, stream>>>(nrm, w1b + (size_t)i * FFD * DM, hid, nullptr, nullptr, nullptr, 32, DM, FFD);
            gemm_bb<2><<<256, 256, 0, stream>>>(hid, w2b + (size_t)i * DM * FFD, nullptr, x, nullptr, nullptr, 8, FFD, DM);
        }
    }

    norm_kernel<<<TT, 256, 0, stream>>>(x, nrm);
    for (int c = 0; c < 3; ++c) {
        gemm_bb<0><<<(LCHUNK / 128) * 32, 256, 0, stream>>>(
            nrm, lmb + (size_t)c * LCHUNK * DM, lchunk, nullptr, nullptr, nullptr, LCHUNK / 128, DM, LCHUNK);
        loss_part_kernel<<<TT, 256, 0, stream>>>(lchunk, target, mbuf, lbuf, zbuf,
                                                 out, c * LCHUNK, LCHUNK, c == 2);
    }
}

// Round 6
// 1498.462 us; speedup vs baseline: 3.3345x; 1.0949x over previous
//
#include <hip/hip_runtime.h>
#include <hip/hip_bf16.h>

#define TT 4096
#define SS 2048
#define BBATCH 2
#define DM 1024
#define NH 16
#define HD 64
#define FFD 4096
#define NL 4
#define VV 18691
#define VP 18816
#define APITCH 72
#define LCHUNK 6272
#define SENT 0x3FFFFFFF

typedef __bf16 bf16x8 __attribute__((ext_vector_type(8)));
typedef float f32x4 __attribute__((ext_vector_type(4)));
typedef const __attribute__((address_space(1))) void* gas_t;
typedef __attribute__((address_space(3))) void* las_t;

__device__ __forceinline__ float bfb2f(unsigned short u) {
    union { unsigned int i; float f; } x;
    x.i = ((unsigned int)u) << 16;
    return x.f;
}
__device__ __forceinline__ unsigned short f2bfb(float f) {
    union { float f; unsigned int i; } x;
    x.f = f;
    unsigned int r = 0x7fffu + ((x.i >> 16) & 1u);
    x.i += r;
    return (unsigned short)(x.i >> 16);
}

__device__ __forceinline__ float wave_sum(float v) {
#pragma unroll
    for (int o = 32; o; o >>= 1) v += __shfl_xor(v, o, 64);
    return v;
}

__device__ __forceinline__ float block_sum256(float v) {
    __shared__ float sb[4];
    v = wave_sum(v);
    int wid = threadIdx.x >> 6;
    if ((threadIdx.x & 63) == 0) sb[wid] = v;
    __syncthreads();
    float t = sb[0] + sb[1] + sb[2] + sb[3];
    __syncthreads();
    return t;
}

// ---- weight fp32 -> bf16 conversion ----
__global__ __launch_bounds__(256) void cvtw_kernel(const float* __restrict__ src,
                                                   unsigned short* __restrict__ dst, int n)
{
    int i = (blockIdx.x * 256 + threadIdx.x) * 4;
    if (i >= n) return;
    float4 f = *reinterpret_cast<const float4*>(src + i);
    ushort4 u;
    u.x = f2bfb(f.x); u.y = f2bfb(f.y); u.z = f2bfb(f.z); u.w = f2bfb(f.w);
    *reinterpret_cast<ushort4*>(dst + i) = u;
}

__global__ __launch_bounds__(256) void cvtpad_kernel(const float* __restrict__ src,
                                                     unsigned short* __restrict__ dst,
                                                     int nreal, int ntot)
{
    int i = (blockIdx.x * 256 + threadIdx.x) * 4;
    if (i >= ntot) return;
    ushort4 u = {0, 0, 0, 0};
    if (i < nreal) {
        float4 f = *reinterpret_cast<const float4*>(src + i);
        u.x = f2bfb(f.x); u.y = f2bfb(f.y); u.z = f2bfb(f.z); u.w = f2bfb(f.w);
    }
    *reinterpret_cast<ushort4*>(dst + i) = u;
}

// x = rms_norm(wte[idx]); x0 = bf16(x); levels[t]
__global__ __launch_bounds__(256) void embed_kernel(
    const int* __restrict__ idx, const float* __restrict__ wte,
    float* __restrict__ x, unsigned short* __restrict__ x0, int* __restrict__ levels)
{
    int t = blockIdx.x;
    int id = idx[t];
    const float* row = wte + (size_t)id * DM;
    float4 v = *reinterpret_cast<const float4*>(row + threadIdx.x * 4);
    float ss = v.x * v.x + v.y * v.y + v.z * v.z + v.w * v.w;
    float tot = block_sum256(ss);
    float rs = rsqrtf(tot / (float)DM + 1e-6f);
    float4 o;
    o.x = v.x * rs; o.y = v.y * rs; o.z = v.z * rs; o.w = v.w * rs;
    size_t off = (size_t)t * DM + threadIdx.x * 4;
    *reinterpret_cast<float4*>(x + off) = o;
    ushort4 ub;
    ub.x = f2bfb(o.x); ub.y = f2bfb(o.y); ub.z = f2bfb(o.z); ub.w = f2bfb(o.w);
    *reinterpret_cast<ushort4*>(x0 + off) = ub;
    if (threadIdx.x == 0) levels[t] = (id >= 16385) + (id >= 18434);
}

// per-batch ascending list of positions with level>0
__global__ __launch_bounds__(256) void pack_kernel(
    const int* __restrict__ levels, int* __restrict__ gpos, int* __restrict__ nbuf)
{
    int b = blockIdx.x;
    const int* lv = levels + b * SS;
    int* gp = gpos + b * SS;
    __shared__ int wsum[4];
    __shared__ int base;
    if (threadIdx.x == 0) base = 0;
    __syncthreads();
    int lane = threadIdx.x & 63, w = threadIdx.x >> 6;
    for (int c = 0; c < SS; c += 256) {
        int s = c + threadIdx.x;
        int flag = (lv[s] > 0) ? 1 : 0;
        unsigned long long mask = __ballot(flag);
        int pre = __popcll(mask & ((1ull << lane) - 1ull));
        int wtot = __popcll(mask);
        if (lane == 0) wsum[w] = wtot;
        __syncthreads();
        int woff = 0;
#pragma unroll
        for (int i = 0; i < 4; ++i) if (i < w) woff += wsum[i];
        int tot = wsum[0] + wsum[1] + wsum[2] + wsum[3];
        int mybase = base;
        if (flag) gp[mybase + woff + pre] = s;
        __syncthreads();
        if (threadIdx.x == 0) base += tot;
        __syncthreads();
    }
    int nb = base;
    int nbp = (nb + 63) & ~63;
    for (int i = nb + threadIdx.x; i < SS; i += 256) gp[i] = SENT;
    if (threadIdx.x == 0) { nbuf[b] = nb; nbuf[BBATCH + b] = nbp; }
}

// gather roped K and mixed V rows of level>0 positions into packed buffers
__global__ __launch_bounds__(64) void gather_kernel(
    const unsigned short* __restrict__ kb, const unsigned short* __restrict__ vb,
    const int* __restrict__ gpos, const int* __restrict__ nbuf,
    unsigned short* __restrict__ kp, unsigned short* __restrict__ vp)
{
    int b = blockIdx.x >> 11;
    int j = blockIdx.x & (SS - 1);
    if (j >= nbuf[BBATCH + b]) return;
    int pos = gpos[b * SS + j];
    int lane = threadIdx.x;
    size_t dst = ((size_t)b * SS + j) * DM + lane * 16;
    if (pos < SS) {
        size_t src = ((size_t)b * SS + pos) * DM + lane * 16;
        *reinterpret_cast<uint4*>(kp + dst) = *reinterpret_cast<const uint4*>(kb + src);
        *reinterpret_cast<uint4*>(kp + dst + 8) = *reinterpret_cast<const uint4*>(kb + src + 8);
        *reinterpret_cast<uint4*>(vp + dst) = *reinterpret_cast<const uint4*>(vb + src);
        *reinterpret_cast<uint4*>(vp + dst + 8) = *reinterpret_cast<const uint4*>(vb + src + 8);
    } else {
        uint4 z = {0, 0, 0, 0};
        *reinterpret_cast<uint4*>(kp + dst) = z;
        *reinterpret_cast<uint4*>(kp + dst + 8) = z;
        *reinterpret_cast<uint4*>(vp + dst) = z;
        *reinterpret_cast<uint4*>(vp + dst + 8) = z;
    }
}

// xr = l0*x + l1*x0 (written back to x); out = bf16(rms_norm(xr))
__global__ __launch_bounds__(256) void mixnorm_kernel(
    float* __restrict__ x, const unsigned short* __restrict__ x0,
    const float* __restrict__ lam2, unsigned short* __restrict__ out)
{
    int t = blockIdx.x;
    size_t off = (size_t)t * DM + threadIdx.x * 4;
    float4 xv = *reinterpret_cast<const float4*>(x + off);
    float l0 = lam2[0], l1 = lam2[1];
    ushort4 u = *reinterpret_cast<const ushort4*>(x0 + off);
    float4 r;
    r.x = l0 * xv.x + l1 * bfb2f(u.x);
    r.y = l0 * xv.y + l1 * bfb2f(u.y);
    r.z = l0 * xv.z + l1 * bfb2f(u.z);
    r.w = l0 * xv.w + l1 * bfb2f(u.w);
    float ss = r.x * r.x + r.y * r.y + r.z * r.z + r.w * r.w;
    float tot = block_sum256(ss);
    float rs = rsqrtf(tot / (float)DM + 1e-6f);
    *reinterpret_cast<float4*>(x + off) = r;
    ushort4 ob;
    ob.x = f2bfb(r.x * rs); ob.y = f2bfb(r.y * rs);
    ob.z = f2bfb(r.z * rs); ob.w = f2bfb(r.w * rs);
    *reinterpret_cast<ushort4*>(out + off) = ob;
}

// out = bf16(rms_norm(x)), x unmodified
__global__ __launch_bounds__(256) void norm_kernel(
    const float* __restrict__ x, unsigned short* __restrict__ out)
{
    int t = blockIdx.x;
    size_t off = (size_t)t * DM + threadIdx.x * 4;
    float4 r = *reinterpret_cast<const float4*>(x + off);
    float ss = r.x * r.x + r.y * r.y + r.z * r.z + r.w * r.w;
    float tot = block_sum256(ss);
    float rs = rsqrtf(tot / (float)DM + 1e-6f);
    ushort4 ob;
    ob.x = f2bfb(r.x * rs); ob.y = f2bfb(r.y * rs);
    ob.z = f2bfb(r.z * rs); ob.w = f2bfb(r.w * rs);
    *reinterpret_cast<ushort4*>(out + off) = ob;
}

// ---------- bf16-weight GEMM, m97 structure, 128x128 tile ----------
// EPI 0: C bf16. EPI 1: relu(acc)^2 bf16. EPI 2: Cf fp32 += acc. EPI 3: fused QKV split.
template <int EPI>
__global__ __launch_bounds__(256) void gemm_bb(
    const unsigned short* __restrict__ A, const unsigned short* __restrict__ Bw,
    unsigned short* __restrict__ Cb, float* __restrict__ Cf,
    unsigned short* __restrict__ Kb, unsigned short* __restrict__ Vb,
    int NX, int K, int ldC)
{
    __shared__ unsigned short As[128 * 64];
    __shared__ unsigned short Bs[128 * 64];

    int nwg = gridDim.x;
    int orig = blockIdx.x;
    int qq = nwg >> 3, rr = nwg & 7;
    int xcd = orig & 7, rem = orig >> 3;
    int wg = (xcd < rr ? xcd * (qq + 1) : rr * (qq + 1) + (xcd - rr) * qq) + rem;
    int bx = wg % NX, by = wg / NX;
    int m0 = by * 128, n0 = bx * 128;

    int tid = threadIdx.x, lane = tid & 63, w = tid >> 6;
    int wr = w >> 1, wc = w & 1;
    int rsub = lane >> 3, sl = lane & 7;
    int ssrc = sl ^ rsub;           // inverse-swizzled source slot
    int fr = lane & 15, fh = lane >> 4;

    size_t arow[4], brow[4];
#pragma unroll
    for (int i = 0; i < 4; ++i) {
        int c = 4 * w + i;
        arow[i] = (size_t)(m0 + 8 * c + rsub) * K + ssrc * 8;
        brow[i] = (size_t)(n0 + 8 * c + rsub) * K + ssrc * 8;
    }

    f32x4 acc[4][4];
#pragma unroll
    for (int m = 0; m < 4; ++m)
#pragma unroll
        for (int n = 0; n < 4; ++n) acc[m][n] = 0.0f;

    int NT = K >> 6;
    for (int kt = 0; kt < NT; ++kt) {
        int kb = kt * 64;
#pragma unroll
        for (int i = 0; i < 4; ++i) {
            __builtin_amdgcn_global_load_lds((gas_t)(const void*)(A + arow[i] + kb),
                                             (las_t)(void*)(&As[(4 * w + i) * 512]), 16, 0, 0);
            __builtin_amdgcn_global_load_lds((gas_t)(const void*)(Bw + brow[i] + kb),
                                             (las_t)(void*)(&Bs[(4 * w + i) * 512]), 16, 0, 0);
        }
        __syncthreads();
#pragma unroll
        for (int kk = 0; kk < 2; ++kk) {
            int slot = kk * 4 + fh;
            bf16x8 af[4], bfv[4];
#pragma unroll
            for (int m = 0; m < 4; ++m) {
                int row = wr * 64 + m * 16 + fr;
                af[m] = *reinterpret_cast<const bf16x8*>(&As[row * 64 + ((slot ^ (row & 7)) << 3)]);
            }
#pragma unroll
            for (int n = 0; n < 4; ++n) {
                int row = wc * 64 + n * 16 + fr;
                bfv[n] = *reinterpret_cast<const bf16x8*>(&Bs[row * 64 + ((slot ^ (row & 7)) << 3)]);
            }
#pragma unroll
            for (int m = 0; m < 4; ++m)
#pragma unroll
                for (int n = 0; n < 4; ++n)
                    acc[m][n] = __builtin_amdgcn_mfma_f32_16x16x32_bf16(af[m], bfv[n], acc[m][n], 0, 0, 0);
        }
        __syncthreads();
    }

    int rb = m0 + wr * 64 + fh * 4;
    int cb = n0 + wc * 64 + fr;
    unsigned short* outp = Cb;
    if constexpr (EPI == 3) {
        int mat = n0 >> 10;
        outp = (mat == 0) ? Cb : ((mat == 1) ? Kb : Vb);
    }
#pragma unroll
    for (int n = 0; n < 4; ++n) {
        int gc = cb + n * 16;
#pragma unroll
        for (int m = 0; m < 4; ++m) {
#pragma unroll
            for (int j = 0; j < 4; ++j) {
                int gr = rb + m * 16 + j;
                float val = acc[m][n][j];
                if constexpr (EPI == 0) {
                    Cb[(size_t)gr * ldC + gc] = f2bfb(val);
                } else if constexpr (EPI == 1) {
                    float rl = fmaxf(val, 0.0f);
                    Cb[(size_t)gr * ldC + gc] = f2bfb(rl * rl);
                } else if constexpr (EPI == 2) {
                    size_t o = (size_t)gr * ldC + gc;
                    Cf[o] = Cf[o] + val;
                } else {
                    outp[(size_t)gr * DM + (gc & 1023)] = f2bfb(val);
                }
            }
        }
    }
}

// ---------- BM=64 variant for small-N GEMMs (wo, w2): 2x the blocks ----------
template <int EPI>
__global__ __launch_bounds__(256) void gemm_bb64(
    const unsigned short* __restrict__ A, const unsigned short* __restrict__ Bw,
    unsigned short* __restrict__ Cb, float* __restrict__ Cf,
    int NX, int K, int ldC)
{
    __shared__ unsigned short As[64 * 64];
    __shared__ unsigned short Bs[128 * 64];

    int nwg = gridDim.x;
    int orig = blockIdx.x;
    int qq = nwg >> 3, rr = nwg & 7;
    int xcd = orig & 7, rem = orig >> 3;
    int wg = (xcd < rr ? xcd * (qq + 1) : rr * (qq + 1) + (xcd - rr) * qq) + rem;
    int bx = wg % NX, by = wg / NX;
    int m0 = by * 64, n0 = bx * 128;

    int tid = threadIdx.x, lane = tid & 63, w = tid >> 6;
    int wr = w >> 1, wc = w & 1;
    int rsub = lane >> 3, sl = lane & 7;
    int ssrc = sl ^ rsub;
    int fr = lane & 15, fh = lane >> 4;

    size_t arow[2], brow[4];
#pragma unroll
    for (int i = 0; i < 2; ++i) {
        int c = 2 * w + i;
        arow[i] = (size_t)(m0 + 8 * c + rsub) * K + ssrc * 8;
    }
#pragma unroll
    for (int i = 0; i < 4; ++i) {
        int c = 4 * w + i;
        brow[i] = (size_t)(n0 + 8 * c + rsub) * K + ssrc * 8;
    }

    f32x4 acc[2][4];
#pragma unroll
    for (int m = 0; m < 2; ++m)
#pragma unroll
        for (int n = 0; n < 4; ++n) acc[m][n] = 0.0f;

    int NT = K >> 6;
    for (int kt = 0; kt < NT; ++kt) {
        int kb = kt * 64;
#pragma unroll
        for (int i = 0; i < 2; ++i)
            __builtin_amdgcn_global_load_lds((gas_t)(const void*)(A + arow[i] + kb),
                                             (las_t)(void*)(&As[(2 * w + i) * 512]), 16, 0, 0);
#pragma unroll
        for (int i = 0; i < 4; ++i)
            __builtin_amdgcn_global_load_lds((gas_t)(const void*)(Bw + brow[i] + kb),
                                             (las_t)(void*)(&Bs[(4 * w + i) * 512]), 16, 0, 0);
        __syncthreads();
#pragma unroll
        for (int kk = 0; kk < 2; ++kk) {
            int slot = kk * 4 + fh;
            bf16x8 af[2], bfv[4];
#pragma unroll
            for (int m = 0; m < 2; ++m) {
                int row = wr * 32 + m * 16 + fr;
                af[m] = *reinterpret_cast<const bf16x8*>(&As[row * 64 + ((slot ^ (row & 7)) << 3)]);
            }
#pragma unroll
            for (int n = 0; n < 4; ++n) {
                int row = wc * 64 + n * 16 + fr;
                bfv[n] = *reinterpret_cast<const bf16x8*>(&Bs[row * 64 + ((slot ^ (row & 7)) << 3)]);
            }
#pragma unroll
            for (int m = 0; m < 2; ++m)
#pragma unroll
                for (int n = 0; n < 4; ++n)
                    acc[m][n] = __builtin_amdgcn_mfma_f32_16x16x32_bf16(af[m], bfv[n], acc[m][n], 0, 0, 0);
        }
        __syncthreads();
    }

    int rb = m0 + wr * 32 + fh * 4;
    int cb = n0 + wc * 64 + fr;
#pragma unroll
    for (int n = 0; n < 4; ++n) {
        int gc = cb + n * 16;
#pragma unroll
        for (int m = 0; m < 2; ++m) {
#pragma unroll
            for (int j = 0; j < 4; ++j) {
                int gr = rb + m * 16 + j;
                float val = acc[m][n][j];
                if constexpr (EPI == 0) {
                    Cb[(size_t)gr * ldC + gc] = f2bfb(val);
                } else if constexpr (EPI == 1) {
                    float rl = fmaxf(val, 0.0f);
                    Cb[(size_t)gr * ldC + gc] = f2bfb(rl * rl);
                } else {
                    size_t o = (size_t)gr * ldC + gc;
                    Cf[o] = Cf[o] + val;
                }
            }
        }
    }
}

__global__ void vcopy_kernel(const unsigned short* __restrict__ v, unsigned short* __restrict__ v1)
{
    int i = blockIdx.x * 256 + threadIdx.x;
    reinterpret_cast<ushort4*>(v1)[i] = reinterpret_cast<const ushort4*>(v)[i];
}

__global__ void vmix_kernel(unsigned short* __restrict__ v, const unsigned short* __restrict__ v1,
                            const float* __restrict__ lamb)
{
    int i = blockIdx.x * 256 + threadIdx.x;
    float la = *lamb;
    ushort4 a = reinterpret_cast<const ushort4*>(v)[i];
    ushort4 b = reinterpret_cast<const ushort4*>(v1)[i];
    ushort4 o;
    o.x = f2bfb((1.0f - la) * bfb2f(a.x) + la * bfb2f(b.x));
    o.y = f2bfb((1.0f - la) * bfb2f(a.y) + la * bfb2f(b.y));
    o.z = f2bfb((1.0f - la) * bfb2f(a.z) + la * bfb2f(b.z));
    o.w = f2bfb((1.0f - la) * bfb2f(a.w) + la * bfb2f(b.w));
    reinterpret_cast<ushort4*>(v)[i] = o;
}

// per-(t,h) head rms_norm + rotary; applied in-place to q (blockIdx.y==0) or k (==1)
__global__ __launch_bounds__(256) void rope_kernel(unsigned short* __restrict__ q,
                                                   unsigned short* __restrict__ k)
{
    int wid = threadIdx.x >> 6, lane = threadIdx.x & 63;
    int id = blockIdx.x * 4 + wid; // t*NH + h
    unsigned short* p = blockIdx.y ? k : q;
    int t = id >> 4, h = id & 15;
    int s = t & (SS - 1);
    size_t off = (size_t)t * DM + h * HD + lane;
    float val = bfb2f(p[off]);
    float ss = wave_sum(val * val);
    float rs = rsqrtf(ss / (float)HD + 1e-6f);
    float nv = val * rs;
    float other = __shfl_xor(nv, 32, 64);
    int j = lane & 31;
    float invf = exp2f(-(float)j * 0.41524101186092025f);
    float fr = (float)s * invf;
    float sn, cs;
    sincosf(fr, &sn, &cs);
    float outv = (lane < 32) ? (nv * cs + other * sn) : (nv * cs - other * sn);
    p[off] = f2bfb(outv);
}

// MFMA flash attention, mask-sparse: local sliding-window pass + packed level>0 pass.
__global__ __launch_bounds__(256) void attn_mfma_kernel(
    const unsigned short* __restrict__ q, const unsigned short* __restrict__ k,
    const unsigned short* __restrict__ v,
    const unsigned short* __restrict__ kp, const unsigned short* __restrict__ vp,
    const int* __restrict__ gpos, const int* __restrict__ nbuf,
    unsigned short* __restrict__ y)
{
    __shared__ unsigned short Qs[64][APITCH];
    __shared__ unsigned short Ks[64][APITCH];
    __shared__ unsigned short Vt[64][APITCH];
    __shared__ unsigned short Ps[64][APITCH];
    __shared__ int posS[64];

    int bh = blockIdx.x;
    int b = bh >> 4, h = bh & 15;
    int q0 = blockIdx.y * 64;
    size_t base = (size_t)b * SS * DM + h * HD;
    int tid = threadIdx.x;
    int lane = tid & 63, w = tid >> 6;
    int srow = tid >> 2, sc = tid & 3;

    {
        const unsigned short* src = q + base + (size_t)(q0 + srow) * DM;
        *reinterpret_cast<uint4*>(&Qs[srow][sc * 8]) = *reinterpret_cast<const uint4*>(src + sc * 8);
        *reinterpret_cast<uint4*>(&Qs[srow][(sc + 4) * 8]) = *reinterpret_cast<const uint4*>(src + (sc + 4) * 8);
    }
    __syncthreads();

    int fr = lane & 15, fc = (lane >> 4) * 8;
    int rj = (lane >> 4) * 4;

    bf16x8 qa[2];
    qa[0] = *reinterpret_cast<const bf16x8*>(&Qs[w * 16 + fr][fc]);
    qa[1] = *reinterpret_cast<const bf16x8*>(&Qs[w * 16 + fr][32 + fc]);

    float mreg[4], lreg[4];
    f32x4 yacc[4];
#pragma unroll
    for (int j = 0; j < 4; ++j) { mreg[j] = -1e30f; lreg[j] = 0.0f; yacc[j] = 0.0f; }

    int nbp = nbuf[BBATCH + b];

    int t0 = (q0 >= 256) ? ((q0 - 256) >> 6) : 0;
    int t1 = q0 >> 6;
    for (int pass = 0; pass < 2; ++pass) {
        int kt_begin = (pass == 0) ? t0 : 0;
        int kt_end = (pass == 0) ? (t1 + 1) : (nbp >> 6);
        for (int kt = kt_begin; kt < kt_end; ++kt) {
            int k0 = kt * 64;
            if (pass == 1) {
                if (gpos[b * SS + k0] > q0 - 194) break;
            }
            __syncthreads();
            {
                const unsigned short* ksrc = (pass == 0) ? (k + base) : (kp + base);
                const unsigned short* vsrc = (pass == 0) ? (v + base) : (vp + base);
                size_t goff = (size_t)(k0 + srow) * DM;
                uint4 kv0 = *reinterpret_cast<const uint4*>(ksrc + goff + sc * 8);
                uint4 kv1 = *reinterpret_cast<const uint4*>(ksrc + goff + (sc + 4) * 8);
                *reinterpret_cast<uint4*>(&Ks[srow][sc * 8]) = kv0;
                *reinterpret_cast<uint4*>(&Ks[srow][(sc + 4) * 8]) = kv1;
                uint4 vv0 = *reinterpret_cast<const uint4*>(vsrc + goff + sc * 8);
                uint4 vv1 = *reinterpret_cast<const uint4*>(vsrc + goff + (sc + 4) * 8);
                const unsigned short* e0 = reinterpret_cast<const unsigned short*>(&vv0);
                const unsigned short* e1 = reinterpret_cast<const unsigned short*>(&vv1);
#pragma unroll
                for (int i = 0; i < 8; ++i) Vt[sc * 8 + i][srow] = e0[i];
#pragma unroll
                for (int i = 0; i < 8; ++i) Vt[(sc + 4) * 8 + i][srow] = e1[i];
                if (pass == 1 && tid < 64) posS[tid] = gpos[b * SS + k0 + tid];
            }
            __syncthreads();

            f32x4 sacc[4];
#pragma unroll
            for (int n = 0; n < 4; ++n) {
                bf16x8 kb0 = *reinterpret_cast<const bf16x8*>(&Ks[n * 16 + fr][fc]);
                bf16x8 kb1 = *reinterpret_cast<const bf16x8*>(&Ks[n * 16 + fr][32 + fc]);
                f32x4 a = {0.0f, 0.0f, 0.0f, 0.0f};
                a = __builtin_amdgcn_mfma_f32_16x16x32_bf16(qa[0], kb0, a, 0, 0, 0);
                a = __builtin_amdgcn_mfma_f32_16x16x32_bf16(qa[1], kb1, a, 0, 0, 0);
                sacc[n] = a;
            }

            float sm[4][4];
            float cm[4] = {-1e30f, -1e30f, -1e30f, -1e30f};
#pragma unroll
            for (int n = 0; n < 4; ++n) {
                int kg = (pass == 0) ? (k0 + n * 16 + fr) : posS[n * 16 + fr];
#pragma unroll
                for (int j = 0; j < 4; ++j) {
                    int qg = q0 + w * 16 + rj + j;
                    bool valid = (pass == 0) ? ((kg <= qg) && (qg - kg <= 256))
                                             : (kg < qg - 256);
                    float s = valid ? sacc[n][j] * 0.125f : -1e30f;
                    sm[n][j] = s;
                    cm[j] = fmaxf(cm[j], s);
                }
            }
#pragma unroll
            for (int j = 0; j < 4; ++j) {
                cm[j] = fmaxf(cm[j], __shfl_xor(cm[j], 1, 64));
                cm[j] = fmaxf(cm[j], __shfl_xor(cm[j], 2, 64));
                cm[j] = fmaxf(cm[j], __shfl_xor(cm[j], 4, 64));
                cm[j] = fmaxf(cm[j], __shfl_xor(cm[j], 8, 64));
            }
            float sj[4], ps[4];
#pragma unroll
            for (int j = 0; j < 4; ++j) {
                float nm = fmaxf(mreg[j], cm[j]);
                sj[j] = __expf(mreg[j] - nm);
                mreg[j] = nm;
                ps[j] = 0.0f;
            }
#pragma unroll
            for (int n = 0; n < 4; ++n) {
#pragma unroll
                for (int j = 0; j < 4; ++j) {
                    float p = (sm[n][j] > -1e29f) ? __expf(sm[n][j] - mreg[j]) : 0.0f;
                    Ps[w * 16 + rj + j][n * 16 + fr] = f2bfb(p);
                    ps[j] += p;
                }
            }
#pragma unroll
            for (int j = 0; j < 4; ++j) {
                float t = ps[j];
                t += __shfl_xor(t, 1, 64); t += __shfl_xor(t, 2, 64);
                t += __shfl_xor(t, 4, 64); t += __shfl_xor(t, 8, 64);
                lreg[j] = lreg[j] * sj[j] + t;
            }
#pragma unroll
            for (int n = 0; n < 4; ++n)
#pragma unroll
                for (int j = 0; j < 4; ++j) yacc[n][j] *= sj[j];

            bf16x8 pa0 = *reinterpret_cast<const bf16x8*>(&Ps[w * 16 + fr][fc]);
            bf16x8 pa1 = *reinterpret_cast<const bf16x8*>(&Ps[w * 16 + fr][32 + fc]);
#pragma unroll
            for (int n = 0; n < 4; ++n) {
                bf16x8 vb0 = *reinterpret_cast<const bf16x8*>(&Vt[n * 16 + fr][fc]);
                bf16x8 vb1 = *reinterpret_cast<const bf16x8*>(&Vt[n * 16 + fr][32 + fc]);
                yacc[n] = __builtin_amdgcn_mfma_f32_16x16x32_bf16(pa0, vb0, yacc[n], 0, 0, 0);
                yacc[n] = __builtin_amdgcn_mfma_f32_16x16x32_bf16(pa1, vb1, yacc[n], 0, 0, 0);
            }
        }
    }

    float inv[4];
#pragma unroll
    for (int j = 0; j < 4; ++j) inv[j] = 1.0f / lreg[j];
#pragma unroll
    for (int n = 0; n < 4; ++n) {
#pragma unroll
        for (int j = 0; j < 4; ++j) {
            int qg = q0 + w * 16 + rj + j;
            y[base + (size_t)qg * DM + n * 16 + fr] = f2bfb(yacc[n][j] * inv[j]);
        }
    }
}

// chunked loss: softcap + partial LSE over [c0, c0+cn), merged into per-token state.
__global__ __launch_bounds__(256) void loss_part_kernel(
    const unsigned short* __restrict__ logits, const int* __restrict__ target,
    float* __restrict__ mbuf, float* __restrict__ lbuf, float* __restrict__ zbuf,
    float* __restrict__ out, int c0, int cn, int last)
{
    int t = blockIdx.x;
    const unsigned short* row = logits + (size_t)t * cn;
    int tg = target[t];
    int tl = tg - c0;
    int lim = min(cn, VV - c0);
    float m = -1e30f, l = 0.0f, ztg = 0.0f;
    for (int i = threadIdx.x; i < lim; i += 256) {
        float z = bfb2f(row[i]);
        z = 30.0f * tanhf(z * (1.0f / 30.0f));
        if (i == tl) ztg = z;
        if (z > m) {
            l = l * __expf(m - z) + 1.0f;
            m = z;
        } else {
            l += __expf(z - m);
        }
    }
    __shared__ float ms[256], ls[256];
    __shared__ float zs;
    if (threadIdx.x == 0) zs = 0.0f;
    ms[threadIdx.x] = m;
    ls[threadIdx.x] = l;
    __syncthreads();
    if (tl >= 0 && tl < lim && threadIdx.x == (tl & 255)) zs = ztg;
    for (int s2 = 128; s2 > 0; s2 >>= 1) {
        __syncthreads();
        if (threadIdx.x < s2) {
            float m2 = ms[threadIdx.x + s2], l2 = ls[threadIdx.x + s2];
            float m1 = ms[threadIdx.x], l1 = ls[threadIdx.x];
            float mm = fmaxf(m1, m2);
            ls[threadIdx.x] = l1 * __expf(m1 - mm) + l2 * __expf(m2 - mm);
            ms[threadIdx.x] = mm;
        }
    }
    __syncthreads();
    if (threadIdx.x == 0) {
        float cmv = ms[0], clv = ls[0], czv = zs;
        float nm, nl, nz;
        if (c0 == 0) {
            nm = cmv; nl = clv; nz = czv;
        } else {
            float pm = mbuf[t], pl = lbuf[t];
            nm = fmaxf(pm, cmv);
            nl = pl * __expf(pm - nm) + clv * __expf(cmv - nm);
            nz = zbuf[t] + czv;
        }
        if (last) {
            float lse = nm + logf(nl);
            bool masked = (tg == 16384) || (tg == 18433) || (tg == 18690);
            out[t] = masked ? 0.0f : (lse - nz);
        } else {
            mbuf[t] = nm; lbuf[t] = nl; zbuf[t] = nz;
        }
    }
}

extern "C" void kernel_launch(void* const* d_in, const int* in_sizes, int n_in,
                              void* d_out, int out_size, void* d_ws, size_t ws_size,
                              hipStream_t stream)
{
    const int* idx = (const int*)d_in[0];
    const int* target = (const int*)d_in[1];
    const float* wte = (const float*)d_in[2];
    const float* lambdas = (const float*)d_in[3];
    const float* lamb = (const float*)d_in[4];
    const float* wq = (const float*)d_in[5];
    const float* wk = (const float*)d_in[6];
    const float* wv = (const float*)d_in[7];
    const float* wo = (const float*)d_in[8];
    const float* w1 = (const float*)d_in[9];
    const float* w2 = (const float*)d_in[10];
    const float* lm_head = (const float*)d_in[11];
    float* out = (float*)d_out;

    char* ws = (char*)d_ws;
    const size_t MB = (size_t)1 << 20;
    float* x            = (float*)(ws);
    unsigned short* x0  = (unsigned short*)(ws + 16 * MB);
    unsigned short* nrm = (unsigned short*)(ws + 24 * MB);
    unsigned short* qb  = (unsigned short*)(ws + 32 * MB);
    unsigned short* kb  = (unsigned short*)(ws + 40 * MB);
    unsigned short* vb  = (unsigned short*)(ws + 48 * MB);
    unsigned short* v1b = (unsigned short*)(ws + 56 * MB);
    unsigned short* yb  = (unsigned short*)(ws + 64 * MB);
    unsigned short* hid = (unsigned short*)(ws + 72 * MB);   // 32 MB; dead during attention
    unsigned short* kp  = (unsigned short*)(ws + 72 * MB);   // packed K (8 MB), overlaps hid
    unsigned short* vp  = (unsigned short*)(ws + 80 * MB);   // packed V (8 MB), overlaps hid
    int* levels         = (int*)(ws + 104 * MB);
    int* gpos           = (int*)(ws + 104 * MB + 64 * 1024);
    int* nbuf           = (int*)(ws + 104 * MB + 128 * 1024);
    float* mbuf         = (float*)(ws + 104 * MB + 256 * 1024);
    float* lbuf         = mbuf + TT;
    float* zbuf         = lbuf + TT;
    unsigned short* wqkvb = (unsigned short*)(ws + 105 * MB); // [NL][3][1024][1024]
    unsigned short* wob = (unsigned short*)(ws + 129 * MB);
    unsigned short* w1b = (unsigned short*)(ws + 137 * MB);
    unsigned short* w2b = (unsigned short*)(ws + 169 * MB);
    unsigned short* lmb = (unsigned short*)(ws + 201 * MB);
    unsigned short* lchunk = qb; // 49 MB spanning qb..hid, dead at lm time
    bool cvt = ws_size >= 238 * MB;

    if (cvt) {
        int n1 = DM * DM;
        int nff = NL * FFD * DM;
        for (int i = 0; i < NL; ++i) {
            cvtw_kernel<<<n1 / 1024, 256, 0, stream>>>(wq + (size_t)i * n1, wqkvb + ((size_t)i * 3 + 0) * n1, n1);
            cvtw_kernel<<<n1 / 1024, 256, 0, stream>>>(wk + (size_t)i * n1, wqkvb + ((size_t)i * 3 + 1) * n1, n1);
            cvtw_kernel<<<n1 / 1024, 256, 0, stream>>>(wv + (size_t)i * n1, wqkvb + ((size_t)i * 3 + 2) * n1, n1);
        }
        cvtw_kernel<<<NL * n1 / 1024, 256, 0, stream>>>(wo, wob, NL * n1);
        cvtw_kernel<<<nff / 1024, 256, 0, stream>>>(w1, w1b, nff);
        cvtw_kernel<<<nff / 1024, 256, 0, stream>>>(w2, w2b, nff);
        cvtpad_kernel<<<(VP * DM) / 1024, 256, 0, stream>>>(lm_head, lmb, VV * DM, VP * DM);
    }

    embed_kernel<<<TT, 256, 0, stream>>>(idx, wte, x, x0, levels);
    pack_kernel<<<BBATCH, 256, 0, stream>>>(levels, gpos, nbuf);

    for (int i = 0; i < NL; ++i) {
        mixnorm_kernel<<<TT, 256, 0, stream>>>(x, x0, lambdas + 2 * i, nrm);
        if (cvt) {
            gemm_bb<3><<<768, 256, 0, stream>>>(nrm, wqkvb + (size_t)i * 3 * DM * DM,
                                                qb, nullptr, kb, vb, 24, DM, DM);
        }
        if (i == 0)
            vcopy_kernel<<<TT * DM / 1024, 256, 0, stream>>>(vb, v1b);
        else
            vmix_kernel<<<TT * DM / 1024, 256, 0, stream>>>(vb, v1b, lamb + i);
        rope_kernel<<<dim3(TT * NH / 4, 2), 256, 0, stream>>>(qb, kb);
        gather_kernel<<<BBATCH * SS, 64, 0, stream>>>(kb, vb, gpos, nbuf, kp, vp);
        attn_mfma_kernel<<<dim3(BBATCH * NH, SS / 64), 256, 0, stream>>>(qb, kb, vb, kp, vp, gpos, nbuf, yb);
        if (cvt) {
            gemm_bb64<2><<<512, 256, 0, stream>>>(yb, wob + (size_t)i * DM * DM, nullptr, x, 8, DM, DM);
            norm_kernel<<<TT, 256, 0, stream>>>(x, nrm);
            gemm_bb<1><<<1024, 256, 0, stream>>>(nrm, w1b + (size_t)i * FFD * DM, hid, nullptr, nullptr, nullptr, 32, DM, FFD);
            gemm_bb64<2><<<512, 256, 0, stream>>>(hid, w2b + (size_t)i * DM * FFD, nullptr, x, 8, FFD, DM);
        }
    }

    norm_kernel<<<TT, 256, 0, stream>>>(x, nrm);
    for (int c = 0; c < 3; ++c) {
        gemm_bb<0><<<(LCHUNK / 128) * 32, 256, 0, stream>>>(
            nrm, lmb + (size_t)c * LCHUNK * DM, lchunk, nullptr, nullptr, nullptr, LCHUNK / 128, DM, LCHUNK);
        loss_part_kernel<<<TT, 256, 0, stream>>>(lchunk, target, mbuf, lbuf, zbuf,
                                                 out, c * LCHUNK, LCHUNK, c == 2);
    }
}